// Round 2
// baseline (728.811 us; speedup 1.0000x reference)
//
#include <hip/hip_runtime.h>
#include <hip/hip_bf16.h>

#define N_NODES 20000
#define F_IN 512

// ---------------------------------------------------------------- CSR build
__global__ void zero_int_k(int* p, int n) {
    int i = blockIdx.x * blockDim.x + threadIdx.x;
    if (i < n) p[i] = 0;
}

__global__ void hist_k(const int* __restrict__ ei, int E0, int N, int* __restrict__ deg) {
    int e = blockIdx.x * blockDim.x + threadIdx.x;
    int Etot = E0 + N;
    if (e >= Etot) return;
    int dst = (e < E0) ? ei[E0 + e] : (e - E0);
    atomicAdd(&deg[dst], 1);
}

// single block, 1024 threads: exclusive scan of deg -> rp, fp ; also dis = rsqrt(deg)
__global__ __launch_bounds__(1024) void scan_k(const int* __restrict__ deg, int* __restrict__ rp,
                                               int* __restrict__ fp, float* __restrict__ dis,
                                               int N, int Etot) {
    __shared__ int part[1024];
    int tid = threadIdx.x;
    int chunk = (N + 1023) / 1024;
    int lo = tid * chunk, hi = min(lo + chunk, N);
    int s = 0;
    for (int i = lo; i < hi; i++) s += deg[i];
    part[tid] = s;
    __syncthreads();
    for (int off = 1; off < 1024; off <<= 1) {
        int t = 0;
        if (tid >= off) t = part[tid - off];
        __syncthreads();
        part[tid] += t;
        __syncthreads();
    }
    int run = part[tid] - s;  // exclusive prefix
    for (int i = lo; i < hi; i++) {
        rp[i] = run; fp[i] = run;
        int d = deg[i];
        dis[i] = (d > 0) ? rsqrtf((float)d) : 0.f;
        run += d;
    }
    if (tid == 1023) { rp[N] = Etot; fp[N] = Etot; }
}

__global__ void scatter_k(const int* __restrict__ ei, int E0, int N, int* __restrict__ fp,
                          int* __restrict__ csr_src) {
    int e = blockIdx.x * blockDim.x + threadIdx.x;
    int Etot = E0 + N;
    if (e >= Etot) return;
    int src, dst;
    if (e < E0) { src = ei[e]; dst = ei[E0 + e]; }
    else        { src = e - E0; dst = src; }
    int pos = atomicAdd(&fp[dst], 1);
    csr_src[pos] = src;
}

// ---------------------------------------------------------------- BN affine prep: sc = g*rsqrt(rv+eps), sh = b - rm*sc
__global__ void bnprep_k(const float* __restrict__ g, const float* __restrict__ b,
                         const float* __restrict__ rm, const float* __restrict__ rv,
                         float* __restrict__ sc, float* __restrict__ sh, int n) {
    int i = blockIdx.x * blockDim.x + threadIdx.x;
    if (i >= n) return;
    float s = g[i] * rsqrtf(rv[i] + 1e-5f);
    sc[i] = s;
    sh[i] = b[i] - rm[i] * s;
}

// ---------------------------------------------------------------- tiled fp32 GEMM (64x64, BK=16)
// BNA: apply per-K-channel affine (sc,sh) to A elements on load (fused input BN)
template <bool BNA, bool BIAS, bool RELU>
__global__ __launch_bounds__(256) void gemm64_k(const float* __restrict__ A, const float* __restrict__ B,
                                                const float* __restrict__ sc, const float* __restrict__ sh,
                                                const float* __restrict__ bias, float* __restrict__ C,
                                                int M, int K, int Nc) {
    __shared__ float As[16][68];
    __shared__ float Bs[16][68];
    int bm = blockIdx.y * 64, bn = blockIdx.x * 64;
    int t = threadIdx.x;
    int tr = (t >> 4) << 2;
    int tc = (t & 15) << 2;
    float acc[4][4] = {};
    for (int k0 = 0; k0 < K; k0 += 16) {
#pragma unroll
        for (int i = 0; i < 4; i++) {
            int idx = t + i * 256;
            int r = idx >> 4, c = idx & 15;
            int gr = bm + r;
            float v = 0.f;
            if (gr < M) {
                v = A[(size_t)gr * K + k0 + c];
                if (BNA) v = v * sc[k0 + c] + sh[k0 + c];
            }
            As[c][r] = v;
        }
#pragma unroll
        for (int i = 0; i < 4; i++) {
            int idx = t + i * 256;
            int r = idx >> 6, c = idx & 63;
            Bs[r][c] = B[(size_t)(k0 + r) * Nc + bn + c];
        }
        __syncthreads();
#pragma unroll
        for (int kk = 0; kk < 16; kk++) {
            float a[4], b[4];
#pragma unroll
            for (int i = 0; i < 4; i++) a[i] = As[kk][tr + i];
#pragma unroll
            for (int j = 0; j < 4; j++) b[j] = Bs[kk][tc + j];
#pragma unroll
            for (int i = 0; i < 4; i++)
#pragma unroll
                for (int j = 0; j < 4; j++) acc[i][j] += a[i] * b[j];
        }
        __syncthreads();
    }
#pragma unroll
    for (int i = 0; i < 4; i++) {
        int gr = bm + tr + i;
        if (gr < M) {
#pragma unroll
            for (int j = 0; j < 4; j++) {
                float v = acc[i][j];
                int gc = bn + tc + j;
                if (BIAS) v += bias[gc];
                if (RELU) v = fmaxf(v, 0.f);
                C[(size_t)gr * Nc + gc] = v;
            }
        }
    }
}

// ---------------------------------------------------------------- small GEMM, W cached in LDS
template <int K, int NOUT>
__global__ __launch_bounds__(NOUT) void rowgemm_k(const float* __restrict__ X, const float* __restrict__ W,
                                                  float* __restrict__ out, int N) {
    __shared__ float Ws[K * NOUT];
    __shared__ float Xs[4][K];
    int c = threadIdx.x;
    for (int i = c; i < K * NOUT; i += NOUT) Ws[i] = W[i];
    for (int r0 = blockIdx.x * 4; r0 < N; r0 += gridDim.x * 4) {
        int nr = min(4, N - r0);
        __syncthreads();
        for (int i = c; i < nr * K; i += NOUT) Xs[i / K][i % K] = X[(size_t)r0 * K + i];
        __syncthreads();
        float acc[4] = {0.f, 0.f, 0.f, 0.f};
        for (int k = 0; k < K; k++) {
            float w = Ws[k * NOUT + c];
#pragma unroll
            for (int r = 0; r < 4; r++) acc[r] += Xs[r][k] * w;
        }
        for (int r = 0; r < nr; r++) out[(size_t)(r0 + r) * NOUT + c] = acc[r];
    }
}

// ---------------------------------------------------------------- attention scores
template <int H, int C>
__global__ __launch_bounds__(256) void scores_k(const float* __restrict__ h, const float* __restrict__ a_src,
                                                const float* __restrict__ a_dst, float* __restrict__ ss,
                                                float* __restrict__ sd, int N) {
    int wid = (blockIdx.x * blockDim.x + threadIdx.x) >> 6;
    int lane = threadIdx.x & 63;
    if (wid >= N * H) return;
    int hh = wid % H;
    const float* hp = h + (size_t)(wid / H) * (H * C) + hh * C;
    float s1 = 0.f, s2 = 0.f;
    for (int c = lane; c < C; c += 64) {
        float v = hp[c];
        s1 += v * a_src[hh * C + c];
        s2 += v * a_dst[hh * C + c];
    }
#pragma unroll
    for (int off = 32; off; off >>= 1) {
        s1 += __shfl_down(s1, off);
        s2 += __shfl_down(s2, off);
    }
    if (lane == 0) { ss[wid] = s1; sd[wid] = s2; }
}

// ---------------------------------------------------------------- GAT aggregation + mean + bias + LN + relu
template <int H, int C>
__global__ __launch_bounds__(C) void gat_agg_k(const float* __restrict__ h, const float* __restrict__ ss,
                                               const float* __restrict__ sd, const float* __restrict__ bias,
                                               const float* __restrict__ g, const float* __restrict__ be,
                                               const int* __restrict__ rp, const int* __restrict__ csr_src,
                                               float* __restrict__ out, int N) {
    int n = blockIdx.x;
    int tid = threadIdx.x;
    __shared__ float m_s[H], s_s[H];
    __shared__ int srcs[64];
    __shared__ float aw[64 * H];  // also reused as reduction buffer (64*H >= C)
    int e0 = rp[n], deg = rp[n + 1] - e0;

    if (tid < H) {
        float m = -1e30f, s = 0.f;
        float sdv = sd[n * H + tid];
        for (int k = 0; k < deg; k++) {
            int src = csr_src[e0 + k];
            float e = ss[src * H + tid] + sdv;
            e = (e > 0.f) ? e : 0.2f * e;
            float mn = fmaxf(m, e);
            s = s * __expf(m - mn) + __expf(e - mn);
            m = mn;
        }
        m_s[tid] = m;
        s_s[tid] = s + 1e-16f;
    }
    __syncthreads();

    float acc = 0.f;
    for (int t0 = 0; t0 < deg; t0 += 64) {
        int tl = min(64, deg - t0);
        if (tid < tl) srcs[tid] = csr_src[e0 + t0 + tid];
        __syncthreads();
        for (int idx = tid; idx < tl * H; idx += C) {
            int k = idx / H, hh = idx % H;
            int src = srcs[k];
            float e = ss[src * H + hh] + sd[n * H + hh];
            e = (e > 0.f) ? e : 0.2f * e;
            aw[idx] = __expf(e - m_s[hh]) / s_s[hh];
        }
        __syncthreads();
        for (int k = 0; k < tl; k++) {
            const float* hp = h + (size_t)srcs[k] * (H * C) + tid;
#pragma unroll
            for (int hh = 0; hh < H; hh++) acc += aw[k * H + hh] * hp[hh * C];
        }
        __syncthreads();
    }

    float v = acc * (1.f / H) + bias[tid];
    // LayerNorm over C channels
    float* r1 = aw;
    r1[tid] = v;
    __syncthreads();
    for (int s = C / 2; s > 0; s >>= 1) {
        if (tid < s) r1[tid] += r1[tid + s];
        __syncthreads();
    }
    float mu = r1[0] * (1.f / C);
    __syncthreads();
    float d = v - mu;
    r1[tid] = d * d;
    __syncthreads();
    for (int s = C / 2; s > 0; s >>= 1) {
        if (tid < s) r1[tid] += r1[tid + s];
        __syncthreads();
    }
    float var = r1[0] * (1.f / C);
    float y = d * rsqrtf(var + 1e-5f) * g[tid] + be[tid];
    out[(size_t)n * C + tid] = fmaxf(y, 0.f);
}

// ---------------------------------------------------------------- GCN aggregation + bias + relu
template <int C>
__global__ __launch_bounds__(C) void gcn_agg_k(const float* __restrict__ h, const float* __restrict__ dis,
                                               const float* __restrict__ bias, const int* __restrict__ rp,
                                               const int* __restrict__ csr_src, float* __restrict__ out, int N) {
    int n = blockIdx.x;
    int tid = threadIdx.x;
    __shared__ int srcs[64];
    __shared__ float w[64];
    int e0 = rp[n], deg = rp[n + 1] - e0;
    float dn = dis[n];
    float acc = 0.f;
    for (int t0 = 0; t0 < deg; t0 += 64) {
        int tl = min(64, deg - t0);
        if (tid < tl) {
            int s = csr_src[e0 + t0 + tid];
            srcs[tid] = s;
            w[tid] = dis[s] * dn;
        }
        __syncthreads();
        for (int k = 0; k < tl; k++) acc += w[k] * h[(size_t)srcs[k] * C + tid];
        __syncthreads();
    }
    out[(size_t)n * C + tid] = fmaxf(acc + bias[tid], 0.f);
}

// ---------------------------------------------------------------- fusion: relu(cat(x1g,x2g)@Wf+bf)+skip -> LN
__global__ __launch_bounds__(64) void fusion_k(const float* __restrict__ x1g, const float* __restrict__ x2g,
                                               const float* __restrict__ Wf, const float* __restrict__ bf,
                                               const float* __restrict__ skip, const float* __restrict__ g3,
                                               const float* __restrict__ be3, float* __restrict__ fin, int N) {
    int n = blockIdx.x;
    int c = threadIdx.x;
    __shared__ float cat[192];
    cat[c] = x1g[(size_t)n * 128 + c];
    cat[64 + c] = x1g[(size_t)n * 128 + 64 + c];
    cat[128 + c] = x2g[(size_t)n * 64 + c];
    __syncthreads();
    float acc = bf[c];
    for (int j = 0; j < 192; j++) acc += cat[j] * Wf[j * 64 + c];
    acc = fmaxf(acc, 0.f) + skip[(size_t)n * 64 + c];
    float mu = acc;
#pragma unroll
    for (int off = 32; off; off >>= 1) mu += __shfl_xor(mu, off);
    mu *= (1.f / 64.f);
    float d = acc - mu;
    float var = d * d;
#pragma unroll
    for (int off = 32; off; off >>= 1) var += __shfl_xor(var, off);
    var *= (1.f / 64.f);
    fin[(size_t)n * 64 + c] = d * rsqrtf(var + 1e-5f) * g3[c] + be3[c];
}

// ---------------------------------------------------------------- classifier: Linear->BN->relu->Linear
__global__ __launch_bounds__(64) void classifier_k(const float* __restrict__ fin, const float* __restrict__ Wc1,
                                                   const float* __restrict__ bc1, const float* __restrict__ gbn,
                                                   const float* __restrict__ bbn, const float* __restrict__ rmb,
                                                   const float* __restrict__ rvb, const float* __restrict__ Wc2,
                                                   const float* __restrict__ bc2, float* __restrict__ out, int N) {
    int n = blockIdx.x;
    int t = threadIdx.x;
    __shared__ float f[64];
    __shared__ float hbuf[32];
    f[t] = fin[(size_t)n * 64 + t];
    __syncthreads();
    if (t < 32) {
        float acc = bc1[t];
        for (int j = 0; j < 64; j++) acc += f[j] * Wc1[j * 32 + t];
        acc = (acc - rmb[t]) * rsqrtf(rvb[t] + 1e-5f) * gbn[t] + bbn[t];
        hbuf[t] = fmaxf(acc, 0.f);
    }
    __syncthreads();
    if (t < 5) {
        float acc = bc2[t];
        for (int j = 0; j < 32; j++) acc += hbuf[j] * Wc2[j * 5 + t];
        out[(size_t)n * 5 + t] = acc;
    }
}

// ================================================================ launch
extern "C" void kernel_launch(void* const* d_in, const int* in_sizes, int n_in,
                              void* d_out, int out_size, void* d_ws, size_t ws_size,
                              hipStream_t stream) {
    const float* x   = (const float*)d_in[0];
    const int*   ei  = (const int*)d_in[1];
    const float* gin = (const float*)d_in[2];
    const float* bti = (const float*)d_in[3];
    const float* rmi = (const float*)d_in[4];
    const float* rvi = (const float*)d_in[5];
    const float* W1  = (const float*)d_in[6];
    const float* as1 = (const float*)d_in[7];
    const float* ad1 = (const float*)d_in[8];
    const float* b1  = (const float*)d_in[9];
    const float* Wg1 = (const float*)d_in[10];
    const float* bg1 = (const float*)d_in[11];
    const float* W2  = (const float*)d_in[12];
    const float* as2 = (const float*)d_in[13];
    const float* ad2 = (const float*)d_in[14];
    const float* b2  = (const float*)d_in[15];
    const float* Wg2 = (const float*)d_in[16];
    const float* bg2 = (const float*)d_in[17];
    const float* Ws  = (const float*)d_in[18];
    const float* bs  = (const float*)d_in[19];
    const float* Wf  = (const float*)d_in[20];
    const float* bf  = (const float*)d_in[21];
    const float* g1  = (const float*)d_in[22];
    const float* be1 = (const float*)d_in[23];
    const float* g2  = (const float*)d_in[24];
    const float* be2 = (const float*)d_in[25];
    const float* g3  = (const float*)d_in[26];
    const float* be3 = (const float*)d_in[27];
    const float* Wc1 = (const float*)d_in[28];
    const float* bc1 = (const float*)d_in[29];
    const float* gbn = (const float*)d_in[30];
    const float* bbn = (const float*)d_in[31];
    const float* rmb = (const float*)d_in[32];
    const float* rvb = (const float*)d_in[33];
    const float* Wc2 = (const float*)d_in[34];
    const float* bc2 = (const float*)d_in[35];
    float* out = (float*)d_out;

    const int N = in_sizes[0] / F_IN;          // 20000
    const int E0 = in_sizes[1] / 2;            // 160000
    const int Etot = E0 + N;                   // 180000

    // ---- workspace carve-up (bump allocator, 256B aligned) — ~68 MB total
    char* wp = (char*)d_ws;
    auto alloc = [&](size_t bytes) -> void* {
        void* p = (void*)wp;
        wp += (bytes + 255) & ~(size_t)255;
        return p;
    };
    float* h1   = (float*)alloc((size_t)N * 512 * 4);   // region aliased after GAT1
    float* ss1  = (float*)alloc((size_t)N * 4 * 4);
    float* sd1  = (float*)alloc((size_t)N * 4 * 4);
    float* x1   = (float*)alloc((size_t)N * 128 * 4);
    float* x2g  = (float*)alloc((size_t)N * 64 * 4);
    float* skip = (float*)alloc((size_t)N * 64 * 4);
    float* fin  = (float*)alloc((size_t)N * 64 * 4);
    float* ss2  = (float*)alloc((size_t)N * 2 * 4);
    float* sd2  = (float*)alloc((size_t)N * 2 * 4);
    float* dis  = (float*)alloc((size_t)N * 4);
    float* sc   = (float*)alloc((size_t)F_IN * 4);
    float* sh   = (float*)alloc((size_t)F_IN * 4);
    int* deg    = (int*)alloc((size_t)N * 4);
    int* rp     = (int*)alloc((size_t)(N + 1) * 4);
    int* fp     = (int*)alloc((size_t)(N + 1) * 4);
    int* csr    = (int*)alloc((size_t)Etot * 4);
    // aliases inside h1's region (h1 dead after GAT1 aggregation)
    float* hg1 = h1;                    // N*128
    float* x1g = h1 + (size_t)N * 128;  // N*128
    float* h2  = h1 + (size_t)N * 256;  // N*128
    float* x2  = h1 + (size_t)N * 384;  // N*64
    float* hg2 = h1 + (size_t)N * 448;  // N*64  (exactly fills N*512)

    // ---- CSR build + BN affine prep
    zero_int_k<<<(N + 255) / 256, 256, 0, stream>>>(deg, N);
    hist_k<<<(Etot + 255) / 256, 256, 0, stream>>>(ei, E0, N, deg);
    scan_k<<<1, 1024, 0, stream>>>(deg, rp, fp, dis, N, Etot);
    scatter_k<<<(Etot + 255) / 256, 256, 0, stream>>>(ei, E0, N, fp, csr);
    bnprep_k<<<2, 256, 0, stream>>>(gin, bti, rmi, rvi, sc, sh, F_IN);

    // ---- GAT1: h1 = bn(x) @ W1 ; scores ; agg+mean+bias -> LN -> relu
    {
        dim3 grid(512 / 64, (N + 63) / 64);
        gemm64_k<true, false, false><<<grid, 256, 0, stream>>>(x, W1, sc, sh, nullptr, h1, N, 512, 512);
    }
    scores_k<4, 128><<<(N * 4 + 3) / 4, 256, 0, stream>>>(h1, as1, ad1, ss1, sd1, N);
    gat_agg_k<4, 128><<<N, 128, 0, stream>>>(h1, ss1, sd1, b1, g1, be1, rp, csr, x1, N);

    // ---- GCN1
    rowgemm_k<128, 128><<<512, 128, 0, stream>>>(x1, Wg1, hg1, N);
    gcn_agg_k<128><<<N, 128, 0, stream>>>(hg1, dis, bg1, rp, csr, x1g, N);

    // ---- GAT2
    rowgemm_k<128, 128><<<512, 128, 0, stream>>>(x1g, W2, h2, N);
    scores_k<2, 64><<<(N * 2 + 3) / 4, 256, 0, stream>>>(h2, as2, ad2, ss2, sd2, N);
    gat_agg_k<2, 64><<<N, 64, 0, stream>>>(h2, ss2, sd2, b2, g2, be2, rp, csr, x2, N);

    // ---- GCN2
    rowgemm_k<64, 64><<<512, 64, 0, stream>>>(x2, Wg2, hg2, N);
    gcn_agg_k<64><<<N, 64, 0, stream>>>(hg2, dis, bg2, rp, csr, x2g, N);

    // ---- skip = relu(bn(x) @ Ws + bs)
    {
        dim3 grid(1, (N + 63) / 64);
        gemm64_k<true, true, true><<<grid, 256, 0, stream>>>(x, Ws, sc, sh, bs, skip, N, 512, 64);
    }

    // ---- fusion + LN
    fusion_k<<<N, 64, 0, stream>>>(x1g, x2g, Wf, bf, skip, g3, be3, fin, N);

    // ---- classifier
    classifier_k<<<N, 64, 0, stream>>>(fin, Wc1, bc1, gbn, bbn, rmb, rvb, Wc2, bc2, out, N);
}

// Round 4
// 583.812 us; speedup vs baseline: 1.2484x; 1.2484x over previous
//
#include <hip/hip_runtime.h>
#include <hip/hip_bf16.h>

#define N_NODES 20000
#define F_IN 512

typedef __attribute__((ext_vector_type(8))) short short8;
typedef __attribute__((ext_vector_type(4))) float f32x4;

// ---------------------------------------------------------------- helpers
__device__ __forceinline__ ushort f2bf(float f) {
    uint u = __float_as_uint(f);
    u += 0x7FFF + ((u >> 16) & 1);   // round-to-nearest-even
    return (ushort)(u >> 16);
}
__device__ __forceinline__ float bf2f(ushort h) { return __uint_as_float((uint)h << 16); }

__device__ __forceinline__ void gload_lds16(const void* g, void* l) {
    __builtin_amdgcn_global_load_lds(
        (const __attribute__((address_space(1))) void*)g,
        (__attribute__((address_space(3))) void*)l, 16, 0, 0);
}

// ---------------------------------------------------------------- CSR build
__global__ void zero_int_k(int* p, int n) {
    int i = blockIdx.x * blockDim.x + threadIdx.x;
    if (i < n) p[i] = 0;
}

__global__ void hist_k(const int* __restrict__ ei, int E0, int N, int* __restrict__ deg) {
    int e = blockIdx.x * blockDim.x + threadIdx.x;
    int Etot = E0 + N;
    if (e >= Etot) return;
    int dst = (e < E0) ? ei[E0 + e] : (e - E0);
    atomicAdd(&deg[dst], 1);
}

__global__ __launch_bounds__(1024) void scan_k(const int* __restrict__ deg, int* __restrict__ rp,
                                               int* __restrict__ fp, float* __restrict__ dis,
                                               int N, int Etot) {
    __shared__ int part[1024];
    int tid = threadIdx.x;
    int chunk = (N + 1023) / 1024;
    int lo = tid * chunk, hi = min(lo + chunk, N);
    int s = 0;
    for (int i = lo; i < hi; i++) s += deg[i];
    part[tid] = s;
    __syncthreads();
    for (int off = 1; off < 1024; off <<= 1) {
        int t = 0;
        if (tid >= off) t = part[tid - off];
        __syncthreads();
        part[tid] += t;
        __syncthreads();
    }
    int run = part[tid] - s;  // exclusive prefix
    for (int i = lo; i < hi; i++) {
        rp[i] = run; fp[i] = run;
        int d = deg[i];
        dis[i] = (d > 0) ? rsqrtf((float)d) : 0.f;
        run += d;
    }
    if (tid == 1023) { rp[N] = Etot; fp[N] = Etot; }
}

__global__ void scatter_k(const int* __restrict__ ei, int E0, int N, int* __restrict__ fp,
                          int* __restrict__ csr_src) {
    int e = blockIdx.x * blockDim.x + threadIdx.x;
    int Etot = E0 + N;
    if (e >= Etot) return;
    int src, dst;
    if (e < E0) { src = ei[e]; dst = ei[E0 + e]; }
    else        { src = e - E0; dst = src; }
    int pos = atomicAdd(&fp[dst], 1);
    csr_src[pos] = src;
}

// ---------------------------------------------------------------- BN affine prep
__global__ void bnprep_k(const float* __restrict__ g, const float* __restrict__ b,
                         const float* __restrict__ rm, const float* __restrict__ rv,
                         float* __restrict__ sc, float* __restrict__ sh, int n) {
    int i = blockIdx.x * blockDim.x + threadIdx.x;
    if (i >= n) return;
    float s = g[i] * rsqrtf(rv[i] + 1e-5f);
    sc[i] = s;
    sh[i] = b[i] - rm[i] * s;
}

// ---------------------------------------------------------------- A split: bn(x) -> Ah,Al bf16 [Mpad][512]
__global__ void splitA_k(const float* __restrict__ x, const float* __restrict__ sc,
                         const float* __restrict__ sh, ushort* __restrict__ Ah,
                         ushort* __restrict__ Al, int M, int Mpad) {
    size_t i4 = (size_t)blockIdx.x * blockDim.x + threadIdx.x;
    size_t base = i4 * 4;
    if (base >= (size_t)Mpad * 512) return;
    int row = (int)(base >> 9);
    ushort4 ah = {0, 0, 0, 0}, al = {0, 0, 0, 0};
    if (row < M) {
        float4 v = *(const float4*)&x[base];
        int c = (int)(base & 511);
        float f0 = v.x * sc[c] + sh[c];
        float f1 = v.y * sc[c + 1] + sh[c + 1];
        float f2 = v.z * sc[c + 2] + sh[c + 2];
        float f3 = v.w * sc[c + 3] + sh[c + 3];
        ah.x = f2bf(f0); al.x = f2bf(f0 - bf2f(ah.x));
        ah.y = f2bf(f1); al.y = f2bf(f1 - bf2f(ah.y));
        ah.z = f2bf(f2); al.z = f2bf(f2 - bf2f(ah.z));
        ah.w = f2bf(f3); al.w = f2bf(f3 - bf2f(ah.w));
    }
    *(ushort4*)&Ah[base] = ah;
    *(ushort4*)&Al[base] = al;
}

// ---------------------------------------------------------------- B prep: Bt[n][k] = split(W[k][n]); cols: [W1 | Ws | pad] -> 640 rows
__global__ __launch_bounds__(256) void splitBt_k(const float* __restrict__ W1, const float* __restrict__ Ws,
                                                 ushort* __restrict__ Bth, ushort* __restrict__ Btl) {
    __shared__ float tile[64][65];
    int n0 = blockIdx.x * 64;   // 0..576 step 64 (10 blocks)
    int k0 = blockIdx.y * 64;   // 0..448 step 64 (8 blocks)
    int t = threadIdx.x;
    int a = t >> 6, b = t & 63;
#pragma unroll
    for (int i = 0; i < 16; i++) {
        int kk = a + i * 4, nn = b;
        int gk = k0 + kk, gn = n0 + nn;
        float v;
        if (gn < 512)      v = W1[(size_t)gk * 512 + gn];
        else if (gn < 576) v = Ws[(size_t)gk * 64 + (gn - 512)];
        else               v = 0.f;
        tile[kk][nn] = v;
    }
    __syncthreads();
#pragma unroll
    for (int i = 0; i < 16; i++) {
        int nn = a + i * 4, kk = b;
        float v = tile[kk][nn];
        ushort hi = f2bf(v);
        ushort lo = f2bf(v - bf2f(hi));
        Bth[(size_t)(n0 + nn) * 512 + k0 + kk] = hi;
        Btl[(size_t)(n0 + nn) * 512 + k0 + kk] = lo;
    }
}

// ---------------------------------------------------------------- fused MFMA GEMM: [h1 | skip] = bn(x) @ [W1 | Ws]
// split-bf16 3-product; tile 128x128, BK=32, 4 waves; m97-style staging.
__global__ __launch_bounds__(256) void mfma_gemm_k(
    const ushort* __restrict__ Ah, const ushort* __restrict__ Al,
    const ushort* __restrict__ Bth, const ushort* __restrict__ Btl,
    const float* __restrict__ bs, float* __restrict__ h1, float* __restrict__ skip,
    int M, int K) {
    __shared__ ushort Ah_s[128 * 32];
    __shared__ ushort Al_s[128 * 32];
    __shared__ ushort Bh_s[128 * 32];
    __shared__ ushort Bl_s[128 * 32];
    int t = threadIdx.x;
    int w = t >> 6, l = t & 63;
    int bm = blockIdx.y * 128;
    int n0 = blockIdx.x * 128;
    int r0 = (w & 1) * 64, c0 = (w >> 1) * 64;

    f32x4 acc[4][4] = {};

    // staging map: lds elem = t*8 (+2048 for second half of rows); row = elem/32, kofs = elem%32
    int elem0 = t * 8;
    int rowS = elem0 >> 5, kofs = elem0 & 31;
    const size_t aoff1 = (size_t)(bm + rowS) * 512 + kofs;
    const size_t aoff2 = (size_t)(bm + rowS + 64) * 512 + kofs;
    const size_t boff1 = (size_t)(n0 + rowS) * 512 + kofs;
    const size_t boff2 = (size_t)(n0 + rowS + 64) * 512 + kofs;

    for (int kt = 0; kt < K; kt += 32) {
        gload_lds16(Ah + aoff1 + kt, &Ah_s[elem0]);
        gload_lds16(Ah + aoff2 + kt, &Ah_s[elem0 + 2048]);
        gload_lds16(Al + aoff1 + kt, &Al_s[elem0]);
        gload_lds16(Al + aoff2 + kt, &Al_s[elem0 + 2048]);
        gload_lds16(Bth + boff1 + kt, &Bh_s[elem0]);
        gload_lds16(Bth + boff2 + kt, &Bh_s[elem0 + 2048]);
        gload_lds16(Btl + boff1 + kt, &Bl_s[elem0]);
        gload_lds16(Btl + boff2 + kt, &Bl_s[elem0 + 2048]);
        __syncthreads();

        short8 ah[4], al4[4], bh[4], bl[4];
        int kg = (l >> 4) * 8;
        int lr = l & 15;
#pragma unroll
        for (int f = 0; f < 4; f++) {
            int ra = (r0 + f * 16 + lr) * 32 + kg;
            ah[f]  = *(const short8*)&Ah_s[ra];
            al4[f] = *(const short8*)&Al_s[ra];
            int rb = (c0 + f * 16 + lr) * 32 + kg;
            bh[f] = *(const short8*)&Bh_s[rb];
            bl[f] = *(const short8*)&Bl_s[rb];
        }
#pragma unroll
        for (int fm = 0; fm < 4; fm++)
#pragma unroll
            for (int fn = 0; fn < 4; fn++) {
                acc[fm][fn] = __builtin_amdgcn_mfma_f32_16x16x32_bf16(ah[fm], bh[fn], acc[fm][fn], 0, 0, 0);
                acc[fm][fn] = __builtin_amdgcn_mfma_f32_16x16x32_bf16(ah[fm], bl[fn], acc[fm][fn], 0, 0, 0);
                acc[fm][fn] = __builtin_amdgcn_mfma_f32_16x16x32_bf16(al4[fm], bh[fn], acc[fm][fn], 0, 0, 0);
            }
        __syncthreads();
    }

    // epilogue: C/D layout col=lane&15, row=(lane>>4)*4+reg
#pragma unroll
    for (int fm = 0; fm < 4; fm++) {
        int row_base = bm + r0 + fm * 16 + (l >> 4) * 4;
#pragma unroll
        for (int fn = 0; fn < 4; fn++) {
            int col = n0 + c0 + fn * 16 + (l & 15);
#pragma unroll
            for (int r = 0; r < 4; r++) {
                int row = row_base + r;
                if (row < M) {
                    float v = acc[fm][fn][r];
                    if (col < 512) h1[(size_t)row * 512 + col] = v;
                    else if (col < 576) skip[(size_t)row * 64 + (col - 512)] = fmaxf(v + bs[col - 512], 0.f);
                }
            }
        }
    }
}

// ---------------------------------------------------------------- small GEMM, W cached in LDS
template <int K, int NOUT>
__global__ __launch_bounds__(NOUT) void rowgemm_k(const float* __restrict__ X, const float* __restrict__ W,
                                                  float* __restrict__ out, int N) {
    __shared__ float Ws[K * NOUT];
    __shared__ float Xs[4][K];
    int c = threadIdx.x;
    for (int i = c; i < K * NOUT; i += NOUT) Ws[i] = W[i];
    for (int r0 = blockIdx.x * 4; r0 < N; r0 += gridDim.x * 4) {
        int nr = min(4, N - r0);
        __syncthreads();
        for (int i = c; i < nr * K; i += NOUT) Xs[i / K][i % K] = X[(size_t)r0 * K + i];
        __syncthreads();
        float acc[4] = {0.f, 0.f, 0.f, 0.f};
        for (int k = 0; k < K; k++) {
            float w = Ws[k * NOUT + c];
#pragma unroll
            for (int r = 0; r < 4; r++) acc[r] += Xs[r][k] * w;
        }
        for (int r = 0; r < nr; r++) out[(size_t)(r0 + r) * NOUT + c] = acc[r];
    }
}

// ---------------------------------------------------------------- attention scores
template <int H, int C>
__global__ __launch_bounds__(256) void scores_k(const float* __restrict__ h, const float* __restrict__ a_src,
                                                const float* __restrict__ a_dst, float* __restrict__ ss,
                                                float* __restrict__ sd, int N) {
    int wid = (blockIdx.x * blockDim.x + threadIdx.x) >> 6;
    int lane = threadIdx.x & 63;
    if (wid >= N * H) return;
    int hh = wid % H;
    const float* hp = h + (size_t)(wid / H) * (H * C) + hh * C;
    float s1 = 0.f, s2 = 0.f;
    for (int c = lane; c < C; c += 64) {
        float v = hp[c];
        s1 += v * a_src[hh * C + c];
        s2 += v * a_dst[hh * C + c];
    }
#pragma unroll
    for (int off = 32; off; off >>= 1) {
        s1 += __shfl_down(s1, off);
        s2 += __shfl_down(s2, off);
    }
    if (lane == 0) { ss[wid] = s1; sd[wid] = s2; }
}

// ---------------------------------------------------------------- GAT aggregation + mean + bias + LN + relu
template <int H, int C>
__global__ __launch_bounds__(C) void gat_agg_k(const float* __restrict__ h, const float* __restrict__ ss,
                                               const float* __restrict__ sd, const float* __restrict__ bias,
                                               const float* __restrict__ g, const float* __restrict__ be,
                                               const int* __restrict__ rp, const int* __restrict__ csr_src,
                                               float* __restrict__ out, int N) {
    int n = blockIdx.x;
    int tid = threadIdx.x;
    __shared__ float m_s[H], s_s[H];
    __shared__ int srcs[64];
    __shared__ float aw[64 * H];
    int e0 = rp[n], deg = rp[n + 1] - e0;

    if (tid < H) {
        float m = -1e30f, s = 0.f;
        float sdv = sd[n * H + tid];
        for (int k = 0; k < deg; k++) {
            int src = csr_src[e0 + k];
            float e = ss[src * H + tid] + sdv;
            e = (e > 0.f) ? e : 0.2f * e;
            float mn = fmaxf(m, e);
            s = s * __expf(m - mn) + __expf(e - mn);
            m = mn;
        }
        m_s[tid] = m;
        s_s[tid] = s + 1e-16f;
    }
    __syncthreads();

    float acc = 0.f;
    for (int t0 = 0; t0 < deg; t0 += 64) {
        int tl = min(64, deg - t0);
        if (tid < tl) srcs[tid] = csr_src[e0 + t0 + tid];
        __syncthreads();
        for (int idx = tid; idx < tl * H; idx += C) {
            int k = idx / H, hh = idx % H;
            int src = srcs[k];
            float e = ss[src * H + hh] + sd[n * H + hh];
            e = (e > 0.f) ? e : 0.2f * e;
            aw[idx] = __expf(e - m_s[hh]) / s_s[hh];
        }
        __syncthreads();
        for (int k = 0; k < tl; k++) {
            const float* hp = h + (size_t)srcs[k] * (H * C) + tid;
#pragma unroll
            for (int hh = 0; hh < H; hh++) acc += aw[k * H + hh] * hp[hh * C];
        }
        __syncthreads();
    }

    float v = acc * (1.f / H) + bias[tid];
    float* r1 = aw;
    r1[tid] = v;
    __syncthreads();
    for (int s = C / 2; s > 0; s >>= 1) {
        if (tid < s) r1[tid] += r1[tid + s];
        __syncthreads();
    }
    float mu = r1[0] * (1.f / C);
    __syncthreads();
    float d = v - mu;
    r1[tid] = d * d;
    __syncthreads();
    for (int s = C / 2; s > 0; s >>= 1) {
        if (tid < s) r1[tid] += r1[tid + s];
        __syncthreads();
    }
    float var = r1[0] * (1.f / C);
    float y = d * rsqrtf(var + 1e-5f) * g[tid] + be[tid];
    out[(size_t)n * C + tid] = fmaxf(y, 0.f);
}

// ---------------------------------------------------------------- GCN aggregation + bias + relu
template <int C>
__global__ __launch_bounds__(C) void gcn_agg_k(const float* __restrict__ h, const float* __restrict__ dis,
                                               const float* __restrict__ bias, const int* __restrict__ rp,
                                               const int* __restrict__ csr_src, float* __restrict__ out, int N) {
    int n = blockIdx.x;
    int tid = threadIdx.x;
    __shared__ int srcs[64];
    __shared__ float w[64];
    int e0 = rp[n], deg = rp[n + 1] - e0;
    float dn = dis[n];
    float acc = 0.f;
    for (int t0 = 0; t0 < deg; t0 += 64) {
        int tl = min(64, deg - t0);
        if (tid < tl) {
            int s = csr_src[e0 + t0 + tid];
            srcs[tid] = s;
            w[tid] = dis[s] * dn;
        }
        __syncthreads();
        for (int k = 0; k < tl; k++) acc += w[k] * h[(size_t)srcs[k] * C + tid];
        __syncthreads();
    }
    out[(size_t)n * C + tid] = fmaxf(acc + bias[tid], 0.f);
}

// ---------------------------------------------------------------- fusion: relu(cat(x1g,x2g)@Wf+bf)+skip -> LN
__global__ __launch_bounds__(64) void fusion_k(const float* __restrict__ x1g, const float* __restrict__ x2g,
                                               const float* __restrict__ Wf, const float* __restrict__ bf,
                                               const float* __restrict__ skip, const float* __restrict__ g3,
                                               const float* __restrict__ be3, float* __restrict__ fin, int N) {
    int n = blockIdx.x;
    int c = threadIdx.x;
    __shared__ float cat[192];
    cat[c] = x1g[(size_t)n * 128 + c];
    cat[64 + c] = x1g[(size_t)n * 128 + 64 + c];
    cat[128 + c] = x2g[(size_t)n * 64 + c];
    __syncthreads();
    float acc = bf[c];
    for (int j = 0; j < 192; j++) acc += cat[j] * Wf[j * 64 + c];
    acc = fmaxf(acc, 0.f) + skip[(size_t)n * 64 + c];
    float mu = acc;
#pragma unroll
    for (int off = 32; off; off >>= 1) mu += __shfl_xor(mu, off);
    mu *= (1.f / 64.f);
    float d = acc - mu;
    float var = d * d;
#pragma unroll
    for (int off = 32; off; off >>= 1) var += __shfl_xor(var, off);
    var *= (1.f / 64.f);
    fin[(size_t)n * 64 + c] = d * rsqrtf(var + 1e-5f) * g3[c] + be3[c];
}

// ---------------------------------------------------------------- classifier: Linear->BN->relu->Linear
__global__ __launch_bounds__(64) void classifier_k(const float* __restrict__ fin, const float* __restrict__ Wc1,
                                                   const float* __restrict__ bc1, const float* __restrict__ gbn,
                                                   const float* __restrict__ bbn, const float* __restrict__ rmb,
                                                   const float* __restrict__ rvb, const float* __restrict__ Wc2,
                                                   const float* __restrict__ bc2, float* __restrict__ out, int N) {
    int n = blockIdx.x;
    int t = threadIdx.x;
    __shared__ float f[64];
    __shared__ float hbuf[32];
    f[t] = fin[(size_t)n * 64 + t];
    __syncthreads();
    if (t < 32) {
        float acc = bc1[t];
        for (int j = 0; j < 64; j++) acc += f[j] * Wc1[j * 32 + t];
        acc = (acc - rmb[t]) * rsqrtf(rvb[t] + 1e-5f) * gbn[t] + bbn[t];
        hbuf[t] = fmaxf(acc, 0.f);
    }
    __syncthreads();
    if (t < 5) {
        float acc = bc2[t];
        for (int j = 0; j < 32; j++) acc += hbuf[j] * Wc2[j * 5 + t];
        out[(size_t)n * 5 + t] = acc;
    }
}

// ================================================================ launch
extern "C" void kernel_launch(void* const* d_in, const int* in_sizes, int n_in,
                              void* d_out, int out_size, void* d_ws, size_t ws_size,
                              hipStream_t stream) {
    const float* x   = (const float*)d_in[0];
    const int*   ei  = (const int*)d_in[1];
    const float* gin = (const float*)d_in[2];
    const float* bti = (const float*)d_in[3];
    const float* rmi = (const float*)d_in[4];
    const float* rvi = (const float*)d_in[5];
    const float* W1  = (const float*)d_in[6];
    const float* as1 = (const float*)d_in[7];
    const float* ad1 = (const float*)d_in[8];
    const float* b1  = (const float*)d_in[9];
    const float* Wg1 = (const float*)d_in[10];
    const float* bg1 = (const float*)d_in[11];
    const float* W2  = (const float*)d_in[12];
    const float* as2 = (const float*)d_in[13];
    const float* ad2 = (const float*)d_in[14];
    const float* b2  = (const float*)d_in[15];
    const float* Wg2 = (const float*)d_in[16];
    const float* bg2 = (const float*)d_in[17];
    const float* Ws  = (const float*)d_in[18];
    const float* bs  = (const float*)d_in[19];
    const float* Wf  = (const float*)d_in[20];
    const float* bf  = (const float*)d_in[21];
    const float* g1  = (const float*)d_in[22];
    const float* be1 = (const float*)d_in[23];
    const float* g2  = (const float*)d_in[24];
    const float* be2 = (const float*)d_in[25];
    const float* g3  = (const float*)d_in[26];
    const float* be3 = (const float*)d_in[27];
    const float* Wc1 = (const float*)d_in[28];
    const float* bc1 = (const float*)d_in[29];
    const float* gbn = (const float*)d_in[30];
    const float* bbn = (const float*)d_in[31];
    const float* rmb = (const float*)d_in[32];
    const float* rvb = (const float*)d_in[33];
    const float* Wc2 = (const float*)d_in[34];
    const float* bc2 = (const float*)d_in[35];
    float* out = (float*)d_out;

    const int N = in_sizes[0] / F_IN;          // 20000
    const int E0 = in_sizes[1] / 2;            // 160000
    const int Etot = E0 + N;                   // 180000
    const int Mpad = 20096;                    // 157*128

    // ---- workspace carve-up (bump allocator, 256B aligned) — ~90 MB
    char* wp = (char*)d_ws;
    auto alloc = [&](size_t bytes) -> void* {
        void* p = (void*)wp;
        wp += (bytes + 255) & ~(size_t)255;
        return p;
    };
    float* h1   = (float*)alloc((size_t)N * 512 * 4);     // region aliased after GAT1
    ushort* Ah  = (ushort*)alloc((size_t)Mpad * 512 * 2); // dead after GEMM -> aliased below
    ushort* Al  = (ushort*)alloc((size_t)Mpad * 512 * 2);
    ushort* Bth = (ushort*)alloc((size_t)640 * 512 * 2);
    ushort* Btl = (ushort*)alloc((size_t)640 * 512 * 2);
    float* skip = (float*)alloc((size_t)N * 64 * 4);
    float* ss1  = (float*)alloc((size_t)N * 4 * 4);
    float* sd1  = (float*)alloc((size_t)N * 4 * 4);
    float* ss2  = (float*)alloc((size_t)N * 2 * 4);
    float* sd2  = (float*)alloc((size_t)N * 2 * 4);
    float* dis  = (float*)alloc((size_t)N * 4);
    float* sc   = (float*)alloc((size_t)F_IN * 4);
    float* sh   = (float*)alloc((size_t)F_IN * 4);
    int* deg    = (int*)alloc((size_t)N * 4);
    int* rp     = (int*)alloc((size_t)(N + 1) * 4);
    int* fp     = (int*)alloc((size_t)(N + 1) * 4);
    int* csr    = (int*)alloc((size_t)Etot * 4);
    // aliases inside h1's region (h1 dead after GAT1 aggregation)
    float* hg1 = h1;                    // N*128
    float* x1g = h1 + (size_t)N * 128;  // N*128
    float* h2  = h1 + (size_t)N * 256;  // N*128
    float* x2  = h1 + (size_t)N * 384;  // N*64
    float* hg2 = h1 + (size_t)N * 448;  // N*64
    // aliases inside Ah region (Ah/Al dead after mfma_gemm; these are written after it)
    float* x1  = (float*)Ah;            // N*128  (10.24 MB)
    float* x2g = x1 + (size_t)N * 128;  // N*64   (5.12 MB)
    float* fin = x2g + (size_t)N * 64;  // N*64   (5.12 MB)  — total 20.48 <= 20.57 MB

    // ---- CSR build + BN prep + splits
    zero_int_k<<<(N + 255) / 256, 256, 0, stream>>>(deg, N);
    hist_k<<<(Etot + 255) / 256, 256, 0, stream>>>(ei, E0, N, deg);
    scan_k<<<1, 1024, 0, stream>>>(deg, rp, fp, dis, N, Etot);
    scatter_k<<<(Etot + 255) / 256, 256, 0, stream>>>(ei, E0, N, fp, csr);
    bnprep_k<<<2, 256, 0, stream>>>(gin, bti, rmi, rvi, sc, sh, F_IN);
    splitA_k<<<(int)(((size_t)Mpad * 512 / 4 + 255) / 256), 256, 0, stream>>>(x, sc, sh, Ah, Al, N, Mpad);
    splitBt_k<<<dim3(10, 8), 256, 0, stream>>>(W1, Ws, Bth, Btl);

    // ---- fused GEMM: [h1 | skip] = bn(x) @ [W1 | Ws]  (skip gets +bs, relu)
    mfma_gemm_k<<<dim3(5, 157), 256, 0, stream>>>(Ah, Al, Bth, Btl, bs, h1, skip, N, 512);

    // ---- GAT1 tail
    scores_k<4, 128><<<(N * 4 + 3) / 4, 256, 0, stream>>>(h1, as1, ad1, ss1, sd1, N);
    gat_agg_k<4, 128><<<N, 128, 0, stream>>>(h1, ss1, sd1, b1, g1, be1, rp, csr, x1, N);

    // ---- GCN1
    rowgemm_k<128, 128><<<512, 128, 0, stream>>>(x1, Wg1, hg1, N);
    gcn_agg_k<128><<<N, 128, 0, stream>>>(hg1, dis, bg1, rp, csr, x1g, N);

    // ---- GAT2
    rowgemm_k<128, 128><<<512, 128, 0, stream>>>(x1g, W2, h2, N);
    scores_k<2, 64><<<(N * 2 + 3) / 4, 256, 0, stream>>>(h2, as2, ad2, ss2, sd2, N);
    gat_agg_k<2, 64><<<N, 64, 0, stream>>>(h2, ss2, sd2, b2, g2, be2, rp, csr, x2, N);

    // ---- GCN2
    rowgemm_k<64, 64><<<512, 64, 0, stream>>>(x2, Wg2, hg2, N);
    gcn_agg_k<64><<<N, 64, 0, stream>>>(hg2, dis, bg2, rp, csr, x2g, N);

    // ---- fusion + LN
    fusion_k<<<N, 64, 0, stream>>>(x1g, x2g, Wf, bf, skip, g3, be3, fin, N);

    // ---- classifier
    classifier_k<<<N, 64, 0, stream>>>(fin, Wc1, bc1, gbn, bbn, rmb, rvb, Wc2, bc2, out, N);
}

// Round 5
// 577.116 us; speedup vs baseline: 1.2628x; 1.0116x over previous
//
#include <hip/hip_runtime.h>
#include <hip/hip_bf16.h>

#define N_NODES 20000
#define F_IN 512

typedef __attribute__((ext_vector_type(8))) short short8;
typedef __attribute__((ext_vector_type(4))) float f32x4;

// ---------------------------------------------------------------- helpers
__device__ __forceinline__ ushort f2bf(float f) {
    uint u = __float_as_uint(f);
    u += 0x7FFF + ((u >> 16) & 1);   // round-to-nearest-even
    return (ushort)(u >> 16);
}
__device__ __forceinline__ float bf2f(ushort h) { return __uint_as_float((uint)h << 16); }

__device__ __forceinline__ void gload_lds16(const void* g, void* l) {
    __builtin_amdgcn_global_load_lds(
        (const __attribute__((address_space(1))) void*)g,
        (__attribute__((address_space(3))) void*)l, 16, 0, 0);
}

// ---------------------------------------------------------------- CSR build
__global__ void zero_int_k(int* p, int n) {
    int i = blockIdx.x * blockDim.x + threadIdx.x;
    if (i < n) p[i] = 0;
}

__global__ void hist_k(const int* __restrict__ ei, int E0, int N, int* __restrict__ deg) {
    int e = blockIdx.x * blockDim.x + threadIdx.x;
    int Etot = E0 + N;
    if (e >= Etot) return;
    int dst = (e < E0) ? ei[E0 + e] : (e - E0);
    atomicAdd(&deg[dst], 1);
}

__global__ __launch_bounds__(1024) void scan_k(const int* __restrict__ deg, int* __restrict__ rp,
                                               int* __restrict__ fp, float* __restrict__ dis,
                                               int N, int Etot) {
    __shared__ int part[1024];
    int tid = threadIdx.x;
    int chunk = (N + 1023) / 1024;
    int lo = tid * chunk, hi = min(lo + chunk, N);
    int s = 0;
    for (int i = lo; i < hi; i++) s += deg[i];
    part[tid] = s;
    __syncthreads();
    for (int off = 1; off < 1024; off <<= 1) {
        int t = 0;
        if (tid >= off) t = part[tid - off];
        __syncthreads();
        part[tid] += t;
        __syncthreads();
    }
    int run = part[tid] - s;  // exclusive prefix
    for (int i = lo; i < hi; i++) {
        rp[i] = run; fp[i] = run;
        int d = deg[i];
        dis[i] = (d > 0) ? rsqrtf((float)d) : 0.f;
        run += d;
    }
    if (tid == 1023) { rp[N] = Etot; fp[N] = Etot; }
}

__global__ void scatter_k(const int* __restrict__ ei, int E0, int N, int* __restrict__ fp,
                          int* __restrict__ csr_src) {
    int e = blockIdx.x * blockDim.x + threadIdx.x;
    int Etot = E0 + N;
    if (e >= Etot) return;
    int src, dst;
    if (e < E0) { src = ei[e]; dst = ei[E0 + e]; }
    else        { src = e - E0; dst = src; }
    int pos = atomicAdd(&fp[dst], 1);
    csr_src[pos] = src;
}

// ---------------------------------------------------------------- BN affine prep
__global__ void bnprep_k(const float* __restrict__ g, const float* __restrict__ b,
                         const float* __restrict__ rm, const float* __restrict__ rv,
                         float* __restrict__ sc, float* __restrict__ sh, int n) {
    int i = blockIdx.x * blockDim.x + threadIdx.x;
    if (i >= n) return;
    float s = g[i] * rsqrtf(rv[i] + 1e-5f);
    sc[i] = s;
    sh[i] = b[i] - rm[i] * s;
}

// ---------------------------------------------------------------- A split: bn(x) -> Ah,Al bf16 [Mpad][512]
__global__ void splitA_k(const float* __restrict__ x, const float* __restrict__ sc,
                         const float* __restrict__ sh, ushort* __restrict__ Ah,
                         ushort* __restrict__ Al, int M, int Mpad) {
    size_t i4 = (size_t)blockIdx.x * blockDim.x + threadIdx.x;
    size_t base = i4 * 4;
    if (base >= (size_t)Mpad * 512) return;
    int row = (int)(base >> 9);
    ushort4 ah = {0, 0, 0, 0}, al = {0, 0, 0, 0};
    if (row < M) {
        float4 v = *(const float4*)&x[base];
        int c = (int)(base & 511);
        float f0 = v.x * sc[c] + sh[c];
        float f1 = v.y * sc[c + 1] + sh[c + 1];
        float f2 = v.z * sc[c + 2] + sh[c + 2];
        float f3 = v.w * sc[c + 3] + sh[c + 3];
        ah.x = f2bf(f0); al.x = f2bf(f0 - bf2f(ah.x));
        ah.y = f2bf(f1); al.y = f2bf(f1 - bf2f(ah.y));
        ah.z = f2bf(f2); al.z = f2bf(f2 - bf2f(ah.z));
        ah.w = f2bf(f3); al.w = f2bf(f3 - bf2f(ah.w));
    }
    *(ushort4*)&Ah[base] = ah;
    *(ushort4*)&Al[base] = al;
}

// ---------------------------------------------------------------- B prep: Bt[n][k] = split(W[k][n]); cols: [W1 | Ws | pad] -> 640 rows
__global__ __launch_bounds__(256) void splitBt_k(const float* __restrict__ W1, const float* __restrict__ Ws,
                                                 ushort* __restrict__ Bth, ushort* __restrict__ Btl) {
    __shared__ float tile[64][65];
    int n0 = blockIdx.x * 64;   // 0..576 step 64 (10 blocks)
    int k0 = blockIdx.y * 64;   // 0..448 step 64 (8 blocks)
    int t = threadIdx.x;
    int a = t >> 6, b = t & 63;
#pragma unroll
    for (int i = 0; i < 16; i++) {
        int kk = a + i * 4, nn = b;
        int gk = k0 + kk, gn = n0 + nn;
        float v;
        if (gn < 512)      v = W1[(size_t)gk * 512 + gn];
        else if (gn < 576) v = Ws[(size_t)gk * 64 + (gn - 512)];
        else               v = 0.f;
        tile[kk][nn] = v;
    }
    __syncthreads();
#pragma unroll
    for (int i = 0; i < 16; i++) {
        int nn = a + i * 4, kk = b;
        float v = tile[kk][nn];
        ushort hi = f2bf(v);
        ushort lo = f2bf(v - bf2f(hi));
        Bth[(size_t)(n0 + nn) * 512 + k0 + kk] = hi;
        Btl[(size_t)(n0 + nn) * 512 + k0 + kk] = lo;
    }
}

// ---------------------------------------------------------------- fused MFMA GEMM: [h1 | skip] = bn(x) @ [W1 | Ws]
// split-bf16 3-product; tile 128x128, BK=32, 4 waves.
// LDS layout [kg][row] (phys = kg*2048B + row*16B) -> conflict-free ds_read_b128;
// the per-lane GLOBAL source is permuted to match (linear LDS dest required by HW).
__global__ __launch_bounds__(256) void mfma_gemm_k(
    const ushort* __restrict__ Ah, const ushort* __restrict__ Al,
    const ushort* __restrict__ Bth, const ushort* __restrict__ Btl,
    const float* __restrict__ bs, float* __restrict__ h1, float* __restrict__ skip,
    int M, int K) {
    __shared__ ushort Ah_s[128 * 32];
    __shared__ ushort Al_s[128 * 32];
    __shared__ ushort Bh_s[128 * 32];
    __shared__ ushort Bl_s[128 * 32];
    int t = threadIdx.x;
    int w = t >> 6, l = t & 63;

    // bijective XCD-chunked swizzle (m204): consecutive logical tiles stay on one XCD
    int nwg = gridDim.x;
    int q = nwg >> 3, r = nwg & 7;
    int xcd = blockIdx.x & 7, lid = blockIdx.x >> 3;
    int wg = (xcd < r) ? xcd * (q + 1) + lid : r * (q + 1) + (xcd - r) * q + lid;
    int by = wg / 5, bx = wg % 5;      // grid logical = 5 (n) x 157 (m), n fastest
    int bm = by * 128;
    int n0 = bx * 128;
    int r0 = (w & 1) * 64, c0 = (w >> 1) * 64;

    f32x4 acc[4][4] = {};

    // staging: thread t stages 16B to phys elem t*8 (call A) and t*8+2048 (call B).
    // phys elem p: kg_p = p>>10, row_p = (p&1023)>>3. Source = row-major global.
    int kg_t = t >> 7;        // 0/1
    int row_t = t & 127;
    const size_t ga1 = (size_t)(bm + row_t) * 512 + kg_t * 8;
    const size_t ga2 = (size_t)(bm + row_t) * 512 + (kg_t + 2) * 8;
    const size_t gb1 = (size_t)(n0 + row_t) * 512 + kg_t * 8;
    const size_t gb2 = (size_t)(n0 + row_t) * 512 + (kg_t + 2) * 8;
    int elem0 = t * 8;

    for (int kt = 0; kt < K; kt += 32) {
        gload_lds16(Ah + ga1 + kt, &Ah_s[elem0]);
        gload_lds16(Ah + ga2 + kt, &Ah_s[elem0 + 2048]);
        gload_lds16(Al + ga1 + kt, &Al_s[elem0]);
        gload_lds16(Al + ga2 + kt, &Al_s[elem0 + 2048]);
        gload_lds16(Bth + gb1 + kt, &Bh_s[elem0]);
        gload_lds16(Bth + gb2 + kt, &Bh_s[elem0 + 2048]);
        gload_lds16(Btl + gb1 + kt, &Bl_s[elem0]);
        gload_lds16(Btl + gb2 + kt, &Bl_s[elem0 + 2048]);
        __syncthreads();

        short8 ah[4], al4[4], bh[4], bl[4];
        int kgl = l >> 4;          // k-subgroup 0..3
        int lr = l & 15;
#pragma unroll
        for (int f = 0; f < 4; f++) {
            int ra = kgl * 1024 + (r0 + f * 16 + lr) * 8;
            ah[f]  = *(const short8*)&Ah_s[ra];
            al4[f] = *(const short8*)&Al_s[ra];
            int rb = kgl * 1024 + (c0 + f * 16 + lr) * 8;
            bh[f] = *(const short8*)&Bh_s[rb];
            bl[f] = *(const short8*)&Bl_s[rb];
        }
#pragma unroll
        for (int fm = 0; fm < 4; fm++)
#pragma unroll
            for (int fn = 0; fn < 4; fn++) {
                acc[fm][fn] = __builtin_amdgcn_mfma_f32_16x16x32_bf16(ah[fm], bh[fn], acc[fm][fn], 0, 0, 0);
                acc[fm][fn] = __builtin_amdgcn_mfma_f32_16x16x32_bf16(ah[fm], bl[fn], acc[fm][fn], 0, 0, 0);
                acc[fm][fn] = __builtin_amdgcn_mfma_f32_16x16x32_bf16(al4[fm], bh[fn], acc[fm][fn], 0, 0, 0);
            }
        __syncthreads();
    }

    // epilogue: C/D layout col=lane&15, row=(lane>>4)*4+reg
#pragma unroll
    for (int fm = 0; fm < 4; fm++) {
        int row_base = bm + r0 + fm * 16 + (l >> 4) * 4;
#pragma unroll
        for (int fn = 0; fn < 4; fn++) {
            int col = n0 + c0 + fn * 16 + (l & 15);
#pragma unroll
            for (int r2 = 0; r2 < 4; r2++) {
                int row = row_base + r2;
                if (row < M) {
                    float v = acc[fm][fn][r2];
                    if (col < 512) h1[(size_t)row * 512 + col] = v;
                    else if (col < 576) skip[(size_t)row * 64 + (col - 512)] = fmaxf(v + bs[col - 512], 0.f);
                }
            }
        }
    }
}

// ---------------------------------------------------------------- small GEMM, W cached in LDS, 8 rows/iter
template <int K, int NOUT>
__global__ __launch_bounds__(NOUT) void rowgemm_k(const float* __restrict__ X, const float* __restrict__ W,
                                                  float* __restrict__ out, int N) {
    __shared__ float Ws[K * NOUT];
    __shared__ float Xs[8][K];
    int c = threadIdx.x;
    for (int i = c; i < K * NOUT; i += NOUT) Ws[i] = W[i];
    for (int r0 = blockIdx.x * 8; r0 < N; r0 += gridDim.x * 8) {
        int nr = min(8, N - r0);
        __syncthreads();
        for (int i = c; i < nr * K; i += NOUT) Xs[i / K][i % K] = X[(size_t)r0 * K + i];
        __syncthreads();
        float acc[8] = {};
        for (int k = 0; k < K; k++) {
            float w = Ws[k * NOUT + c];
#pragma unroll
            for (int r = 0; r < 8; r++) acc[r] += Xs[r][k] * w;
        }
        for (int r = 0; r < nr; r++) out[(size_t)(r0 + r) * NOUT + c] = acc[r];
    }
}

// ---------------------------------------------------------------- attention scores
template <int H, int C>
__global__ __launch_bounds__(256) void scores_k(const float* __restrict__ h, const float* __restrict__ a_src,
                                                const float* __restrict__ a_dst, float* __restrict__ ss,
                                                float* __restrict__ sd, int N) {
    int wid = (blockIdx.x * blockDim.x + threadIdx.x) >> 6;
    int lane = threadIdx.x & 63;
    if (wid >= N * H) return;
    int hh = wid % H;
    const float* hp = h + (size_t)(wid / H) * (H * C) + hh * C;
    float s1 = 0.f, s2 = 0.f;
    for (int c = lane; c < C; c += 64) {
        float v = hp[c];
        s1 += v * a_src[hh * C + c];
        s2 += v * a_dst[hh * C + c];
    }
#pragma unroll
    for (int off = 32; off; off >>= 1) {
        s1 += __shfl_down(s1, off);
        s2 += __shfl_down(s2, off);
    }
    if (lane == 0) { ss[wid] = s1; sd[wid] = s2; }
}

// ---------------------------------------------------------------- GAT agg: wave-parallel online softmax (+e-cache),
// gather, mean, bias, LN (shuffle), relu.  Requires C/H == 32.
template <int H, int C>
__global__ __launch_bounds__(C) void gat_agg_k(const float* __restrict__ h, const float* __restrict__ ss,
                                               const float* __restrict__ sd, const float* __restrict__ bias,
                                               const float* __restrict__ g, const float* __restrict__ be,
                                               const int* __restrict__ rp, const int* __restrict__ csr_src,
                                               float* __restrict__ out, int N) {
    int n = blockIdx.x;
    int tid = threadIdx.x;
    __shared__ float m_s[H], s_s[H], red[4];
    __shared__ int srcs[64];
    __shared__ float aw[64 * H];
    int e0 = rp[n], deg = rp[n + 1] - e0;
    bool small = (deg <= 64);
    int hh = tid >> 5, l = tid & 31;

    if (small && tid < deg) srcs[tid] = csr_src[e0 + tid];
    __syncthreads();

    // phase 1: per-(head,lane) online max/sum over edges, butterfly merge over 32 lanes
    float sdv = sd[n * H + hh];
    float m = -1e30f, s = 0.f;
    for (int k = l; k < deg; k += 32) {
        int src = small ? srcs[k] : csr_src[e0 + k];
        float e = ss[src * H + hh] + sdv;
        e = (e > 0.f) ? e : 0.2f * e;
        if (small) aw[k * H + hh] = e;
        float mn = fmaxf(m, e);
        s = s * __expf(m - mn) + __expf(e - mn);
        m = mn;
    }
#pragma unroll
    for (int off = 16; off; off >>= 1) {
        float mo = __shfl_xor(m, off), so = __shfl_xor(s, off);
        float mn = fmaxf(m, mo);
        s = s * __expf(m - mn) + so * __expf(mo - mn);
        m = mn;
    }
    if (l == 0) { m_s[hh] = m; s_s[hh] = s + 1e-16f; }
    __syncthreads();

    // phase 2: alpha + gather
    float v = 0.f;
    if (small) {
        for (int idx = tid; idx < deg * H; idx += C) {
            int h2 = idx & (H - 1);
            aw[idx] = __expf(aw[idx] - m_s[h2]) / s_s[h2];
        }
        __syncthreads();
        for (int k = 0; k < deg; k++) {
            const float* hp = h + (size_t)srcs[k] * (H * C) + tid;
#pragma unroll
            for (int h2 = 0; h2 < H; h2++) v += aw[k * H + h2] * hp[h2 * C];
        }
    } else {
        for (int t0 = 0; t0 < deg; t0 += 64) {
            int tl = min(64, deg - t0);
            __syncthreads();
            if (tid < tl) srcs[tid] = csr_src[e0 + t0 + tid];
            __syncthreads();
            for (int idx = tid; idx < tl * H; idx += C) {
                int k = idx / H, h2 = idx & (H - 1);
                float e = ss[srcs[k] * H + h2] + sd[n * H + h2];
                e = (e > 0.f) ? e : 0.2f * e;
                aw[idx] = __expf(e - m_s[h2]) / s_s[h2];
            }
            __syncthreads();
            for (int k = 0; k < tl; k++) {
                const float* hp = h + (size_t)srcs[k] * (H * C) + tid;
#pragma unroll
                for (int h2 = 0; h2 < H; h2++) v += aw[k * H + h2] * hp[h2 * C];
            }
        }
    }

    // phase 3: mean heads + bias + LN (shuffle) + relu
    v = v * (1.f / H) + bias[tid];
    float t1 = v;
#pragma unroll
    for (int off = 32; off; off >>= 1) t1 += __shfl_xor(t1, off);
    float mu;
    if (C == 128) {
        if ((tid & 63) == 0) red[tid >> 6] = t1;
        __syncthreads();
        mu = (red[0] + red[1]) * (1.f / C);
    } else {
        mu = t1 * (1.f / C);
    }
    float d = v - mu;
    float t2 = d * d;
#pragma unroll
    for (int off = 32; off; off >>= 1) t2 += __shfl_xor(t2, off);
    float var;
    if (C == 128) {
        if ((tid & 63) == 0) red[2 + (tid >> 6)] = t2;
        __syncthreads();
        var = (red[2] + red[3]) * (1.f / C);
    } else {
        var = t2 * (1.f / C);
    }
    float y = d * rsqrtf(var + 1e-5f) * g[tid] + be[tid];
    out[(size_t)n * C + tid] = fmaxf(y, 0.f);
}

// ---------------------------------------------------------------- GCN aggregation + bias + relu (used for GCN1)
template <int C>
__global__ __launch_bounds__(C) void gcn_agg_k(const float* __restrict__ h, const float* __restrict__ dis,
                                               const float* __restrict__ bias, const int* __restrict__ rp,
                                               const int* __restrict__ csr_src, float* __restrict__ out, int N) {
    int n = blockIdx.x;
    int tid = threadIdx.x;
    __shared__ int srcs[64];
    __shared__ float w[64];
    int e0 = rp[n], deg = rp[n + 1] - e0;
    float dn = dis[n];
    float acc = 0.f;
    for (int t0 = 0; t0 < deg; t0 += 64) {
        int tl = min(64, deg - t0);
        if (tid < tl) {
            int s = csr_src[e0 + t0 + tid];
            srcs[tid] = s;
            w[tid] = dis[s] * dn;
        }
        __syncthreads();
        for (int k = 0; k < tl; k++) acc += w[k] * h[(size_t)srcs[k] * C + tid];
        __syncthreads();
    }
    out[(size_t)n * C + tid] = fmaxf(acc + bias[tid], 0.f);
}

// ---------------------------------------------------------------- final fused: gcn_agg2 -> fusion+LN -> classifier
__global__ __launch_bounds__(64) void final_fused_k(
    const float* __restrict__ hg2, const float* __restrict__ dis, const float* __restrict__ bg2,
    const int* __restrict__ rp, const int* __restrict__ csr_src,
    const float* __restrict__ x1g, const float* __restrict__ Wf, const float* __restrict__ bf,
    const float* __restrict__ skip, const float* __restrict__ g3, const float* __restrict__ be3,
    const float* __restrict__ Wc1, const float* __restrict__ bc1, const float* __restrict__ gbn,
    const float* __restrict__ bbn, const float* __restrict__ rmb, const float* __restrict__ rvb,
    const float* __restrict__ Wc2, const float* __restrict__ bc2, float* __restrict__ out, int N) {
    int n = blockIdx.x;
    int tid = threadIdx.x;
    __shared__ int srcs[64];
    __shared__ float w[64];
    __shared__ float cat[192];
    __shared__ float fbuf[64];
    __shared__ float hbuf[32];
    int e0 = rp[n], deg = rp[n + 1] - e0;
    float dn = dis[n];
    float acc = 0.f;
    for (int t0 = 0; t0 < deg; t0 += 64) {
        int tl = min(64, deg - t0);
        if (tid < tl) {
            int s = csr_src[e0 + t0 + tid];
            srcs[tid] = s;
            w[tid] = dis[s] * dn;
        }
        __syncthreads();
        for (int k = 0; k < tl; k++) acc += w[k] * hg2[(size_t)srcs[k] * 64 + tid];
        __syncthreads();
    }
    float x2gv = fmaxf(acc + bg2[tid], 0.f);
    cat[tid] = x1g[(size_t)n * 128 + tid];
    cat[64 + tid] = x1g[(size_t)n * 128 + 64 + tid];
    cat[128 + tid] = x2gv;
    __syncthreads();
    float fa = bf[tid];
    for (int j = 0; j < 192; j++) fa += cat[j] * Wf[j * 64 + tid];
    fa = fmaxf(fa, 0.f) + skip[(size_t)n * 64 + tid];
    // LN over 64 (single wave)
    float t1 = fa;
#pragma unroll
    for (int off = 32; off; off >>= 1) t1 += __shfl_xor(t1, off);
    float mu = t1 * (1.f / 64.f);
    float d = fa - mu;
    float t2 = d * d;
#pragma unroll
    for (int off = 32; off; off >>= 1) t2 += __shfl_xor(t2, off);
    float var = t2 * (1.f / 64.f);
    fbuf[tid] = d * rsqrtf(var + 1e-5f) * g3[tid] + be3[tid];
    __syncthreads();
    if (tid < 32) {
        float a = bc1[tid];
        for (int j = 0; j < 64; j++) a += fbuf[j] * Wc1[j * 32 + tid];
        a = (a - rmb[tid]) * rsqrtf(rvb[tid] + 1e-5f) * gbn[tid] + bbn[tid];
        hbuf[tid] = fmaxf(a, 0.f);
    }
    __syncthreads();
    if (tid < 5) {
        float a = bc2[tid];
        for (int j = 0; j < 32; j++) a += hbuf[j] * Wc2[j * 5 + tid];
        out[(size_t)n * 5 + tid] = a;
    }
}

// ================================================================ launch
extern "C" void kernel_launch(void* const* d_in, const int* in_sizes, int n_in,
                              void* d_out, int out_size, void* d_ws, size_t ws_size,
                              hipStream_t stream) {
    const float* x   = (const float*)d_in[0];
    const int*   ei  = (const int*)d_in[1];
    const float* gin = (const float*)d_in[2];
    const float* bti = (const float*)d_in[3];
    const float* rmi = (const float*)d_in[4];
    const float* rvi = (const float*)d_in[5];
    const float* W1  = (const float*)d_in[6];
    const float* as1 = (const float*)d_in[7];
    const float* ad1 = (const float*)d_in[8];
    const float* b1  = (const float*)d_in[9];
    const float* Wg1 = (const float*)d_in[10];
    const float* bg1 = (const float*)d_in[11];
    const float* W2  = (const float*)d_in[12];
    const float* as2 = (const float*)d_in[13];
    const float* ad2 = (const float*)d_in[14];
    const float* b2  = (const float*)d_in[15];
    const float* Wg2 = (const float*)d_in[16];
    const float* bg2 = (const float*)d_in[17];
    const float* Ws  = (const float*)d_in[18];
    const float* bs  = (const float*)d_in[19];
    const float* Wf  = (const float*)d_in[20];
    const float* bf  = (const float*)d_in[21];
    const float* g1  = (const float*)d_in[22];
    const float* be1 = (const float*)d_in[23];
    const float* g2  = (const float*)d_in[24];
    const float* be2 = (const float*)d_in[25];
    const float* g3  = (const float*)d_in[26];
    const float* be3 = (const float*)d_in[27];
    const float* Wc1 = (const float*)d_in[28];
    const float* bc1 = (const float*)d_in[29];
    const float* gbn = (const float*)d_in[30];
    const float* bbn = (const float*)d_in[31];
    const float* rmb = (const float*)d_in[32];
    const float* rvb = (const float*)d_in[33];
    const float* Wc2 = (const float*)d_in[34];
    const float* bc2 = (const float*)d_in[35];
    float* out = (float*)d_out;

    const int N = in_sizes[0] / F_IN;          // 20000
    const int E0 = in_sizes[1] / 2;            // 160000
    const int Etot = E0 + N;                   // 180000
    const int Mpad = 20096;                    // 157*128

    // ---- workspace carve-up (bump allocator, 256B aligned)
    char* wp = (char*)d_ws;
    auto alloc = [&](size_t bytes) -> void* {
        void* p = (void*)wp;
        wp += (bytes + 255) & ~(size_t)255;
        return p;
    };
    float* h1   = (float*)alloc((size_t)N * 512 * 4);     // region aliased after GAT1
    ushort* Ah  = (ushort*)alloc((size_t)Mpad * 512 * 2); // dead after GEMM -> aliased below
    ushort* Al  = (ushort*)alloc((size_t)Mpad * 512 * 2);
    ushort* Bth = (ushort*)alloc((size_t)640 * 512 * 2);
    ushort* Btl = (ushort*)alloc((size_t)640 * 512 * 2);
    float* skip = (float*)alloc((size_t)N * 64 * 4);
    float* ss1  = (float*)alloc((size_t)N * 4 * 4);
    float* sd1  = (float*)alloc((size_t)N * 4 * 4);
    float* ss2  = (float*)alloc((size_t)N * 2 * 4);
    float* sd2  = (float*)alloc((size_t)N * 2 * 4);
    float* dis  = (float*)alloc((size_t)N * 4);
    float* sc   = (float*)alloc((size_t)F_IN * 4);
    float* sh   = (float*)alloc((size_t)F_IN * 4);
    int* deg    = (int*)alloc((size_t)N * 4);
    int* rp     = (int*)alloc((size_t)(N + 1) * 4);
    int* fp     = (int*)alloc((size_t)(N + 1) * 4);
    int* csr    = (int*)alloc((size_t)Etot * 4);
    // aliases inside h1's region (h1 dead after GAT1 aggregation)
    float* hg1 = h1;                    // N*128
    float* x1g = h1 + (size_t)N * 128;  // N*128
    float* h2  = h1 + (size_t)N * 256;  // N*128
    float* x2  = h1 + (size_t)N * 384;  // N*64
    float* hg2 = h1 + (size_t)N * 448;  // N*64
    // aliases inside Ah region (Ah/Al dead after mfma_gemm)
    float* x1  = (float*)Ah;            // N*128

    // ---- CSR build + BN prep + splits
    zero_int_k<<<(N + 255) / 256, 256, 0, stream>>>(deg, N);
    hist_k<<<(Etot + 255) / 256, 256, 0, stream>>>(ei, E0, N, deg);
    scan_k<<<1, 1024, 0, stream>>>(deg, rp, fp, dis, N, Etot);
    scatter_k<<<(Etot + 255) / 256, 256, 0, stream>>>(ei, E0, N, fp, csr);
    bnprep_k<<<2, 256, 0, stream>>>(gin, bti, rmi, rvi, sc, sh, F_IN);
    splitA_k<<<(int)(((size_t)Mpad * 512 / 4 + 255) / 256), 256, 0, stream>>>(x, sc, sh, Ah, Al, N, Mpad);
    splitBt_k<<<dim3(10, 8), 256, 0, stream>>>(W1, Ws, Bth, Btl);

    // ---- fused GEMM: [h1 | skip] = bn(x) @ [W1 | Ws]  (skip gets +bs, relu); 1D grid 5*157
    mfma_gemm_k<<<785, 256, 0, stream>>>(Ah, Al, Bth, Btl, bs, h1, skip, N, 512);

    // ---- GAT1 tail
    scores_k<4, 128><<<(N * 4 + 3) / 4, 256, 0, stream>>>(h1, as1, ad1, ss1, sd1, N);
    gat_agg_k<4, 128><<<N, 128, 0, stream>>>(h1, ss1, sd1, b1, g1, be1, rp, csr, x1, N);

    // ---- GCN1
    rowgemm_k<128, 128><<<1280, 128, 0, stream>>>(x1, Wg1, hg1, N);
    gcn_agg_k<128><<<N, 128, 0, stream>>>(hg1, dis, bg1, rp, csr, x1g, N);

    // ---- GAT2
    rowgemm_k<128, 128><<<1280, 128, 0, stream>>>(x1g, W2, h2, N);
    scores_k<2, 64><<<(N * 2 + 3) / 4, 256, 0, stream>>>(h2, as2, ad2, ss2, sd2, N);
    gat_agg_k<2, 64><<<N, 64, 0, stream>>>(h2, ss2, sd2, b2, g2, be2, rp, csr, x2, N);

    // ---- GCN2 dense part
    rowgemm_k<64, 64><<<1280, 64, 0, stream>>>(x2, Wg2, hg2, N);

    // ---- GCN2 agg + fusion + LN + classifier (fused, row-local)
    final_fused_k<<<N, 64, 0, stream>>>(hg2, dis, bg2, rp, csr, x1g, Wf, bf, skip, g3, be3,
                                        Wc1, bc1, gbn, bbn, rmb, rvb, Wc2, bc2, out, N);
}

// Round 6
// 540.528 us; speedup vs baseline: 1.3483x; 1.0677x over previous
//
#include <hip/hip_runtime.h>
#include <hip/hip_bf16.h>

#define N_NODES 20000
#define F_IN 512

typedef __attribute__((ext_vector_type(8))) short short8;
typedef __attribute__((ext_vector_type(4))) float f32x4;

// ---------------------------------------------------------------- helpers
__device__ __forceinline__ ushort f2bf(float f) {
    uint u = __float_as_uint(f);
    u += 0x7FFF + ((u >> 16) & 1);   // round-to-nearest-even
    return (ushort)(u >> 16);
}
__device__ __forceinline__ float bf2f(ushort h) { return __uint_as_float((uint)h << 16); }

__device__ __forceinline__ void gload_lds16(const void* g, void* l) {
    __builtin_amdgcn_global_load_lds(
        (const __attribute__((address_space(1))) void*)g,
        (__attribute__((address_space(3))) void*)l, 16, 0, 0);
}

// ---------------------------------------------------------------- CSR build
__global__ void zero_int_k(int* p, int n) {
    int i = blockIdx.x * blockDim.x + threadIdx.x;
    if (i < n) p[i] = 0;
}

__global__ void hist_k(const int* __restrict__ ei, int E0, int N, int* __restrict__ deg) {
    int e = blockIdx.x * blockDim.x + threadIdx.x;
    int Etot = E0 + N;
    if (e >= Etot) return;
    int dst = (e < E0) ? ei[E0 + e] : (e - E0);
    atomicAdd(&deg[dst], 1);
}

__global__ __launch_bounds__(1024) void scan_k(const int* __restrict__ deg, int* __restrict__ rp,
                                               int* __restrict__ fp, float* __restrict__ dis,
                                               int N, int Etot) {
    __shared__ int part[1024];
    int tid = threadIdx.x;
    int chunk = (N + 1023) / 1024;
    int lo = tid * chunk, hi = min(lo + chunk, N);
    int s = 0;
    for (int i = lo; i < hi; i++) s += deg[i];
    part[tid] = s;
    __syncthreads();
    for (int off = 1; off < 1024; off <<= 1) {
        int t = 0;
        if (tid >= off) t = part[tid - off];
        __syncthreads();
        part[tid] += t;
        __syncthreads();
    }
    int run = part[tid] - s;  // exclusive prefix
    for (int i = lo; i < hi; i++) {
        rp[i] = run; fp[i] = run;
        int d = deg[i];
        dis[i] = (d > 0) ? rsqrtf((float)d) : 0.f;
        run += d;
    }
    if (tid == 1023) { rp[N] = Etot; fp[N] = Etot; }
}

__global__ void scatter_k(const int* __restrict__ ei, int E0, int N, int* __restrict__ fp,
                          int* __restrict__ csr_src) {
    int e = blockIdx.x * blockDim.x + threadIdx.x;
    int Etot = E0 + N;
    if (e >= Etot) return;
    int src, dst;
    if (e < E0) { src = ei[e]; dst = ei[E0 + e]; }
    else        { src = e - E0; dst = src; }
    int pos = atomicAdd(&fp[dst], 1);
    csr_src[pos] = src;
}

// ---------------------------------------------------------------- BN affine prep
__global__ void bnprep_k(const float* __restrict__ g, const float* __restrict__ b,
                         const float* __restrict__ rm, const float* __restrict__ rv,
                         float* __restrict__ sc, float* __restrict__ sh, int n) {
    int i = blockIdx.x * blockDim.x + threadIdx.x;
    if (i >= n) return;
    float s = g[i] * rsqrtf(rv[i] + 1e-5f);
    sc[i] = s;
    sh[i] = b[i] - rm[i] * s;
}

// ---------------------------------------------------------------- A split: bn(x) -> Ah,Al bf16 [Mpad][512]
__global__ void splitA_k(const float* __restrict__ x, const float* __restrict__ sc,
                         const float* __restrict__ sh, ushort* __restrict__ Ah,
                         ushort* __restrict__ Al, int M, int Mpad) {
    size_t i4 = (size_t)blockIdx.x * blockDim.x + threadIdx.x;
    size_t base = i4 * 4;
    if (base >= (size_t)Mpad * 512) return;
    int row = (int)(base >> 9);
    ushort4 ah = {0, 0, 0, 0}, al = {0, 0, 0, 0};
    if (row < M) {
        float4 v = *(const float4*)&x[base];
        int c = (int)(base & 511);
        float f0 = v.x * sc[c] + sh[c];
        float f1 = v.y * sc[c + 1] + sh[c + 1];
        float f2 = v.z * sc[c + 2] + sh[c + 2];
        float f3 = v.w * sc[c + 3] + sh[c + 3];
        ah.x = f2bf(f0); al.x = f2bf(f0 - bf2f(ah.x));
        ah.y = f2bf(f1); al.y = f2bf(f1 - bf2f(ah.y));
        ah.z = f2bf(f2); al.z = f2bf(f2 - bf2f(ah.z));
        ah.w = f2bf(f3); al.w = f2bf(f3 - bf2f(ah.w));
    }
    *(ushort4*)&Ah[base] = ah;
    *(ushort4*)&Al[base] = al;
}

// ---------------------------------------------------------------- B prep: Bt[n][k] = split(W[k][n]); cols: [W1 | Ws | pad] -> 640 rows
__global__ __launch_bounds__(256) void splitBt_k(const float* __restrict__ W1, const float* __restrict__ Ws,
                                                 ushort* __restrict__ Bth, ushort* __restrict__ Btl) {
    __shared__ float tile[64][65];
    int n0 = blockIdx.x * 64;   // 0..576 step 64 (10 blocks)
    int k0 = blockIdx.y * 64;   // 0..448 step 64 (8 blocks)
    int t = threadIdx.x;
    int a = t >> 6, b = t & 63;
#pragma unroll
    for (int i = 0; i < 16; i++) {
        int kk = a + i * 4, nn = b;
        int gk = k0 + kk, gn = n0 + nn;
        float v;
        if (gn < 512)      v = W1[(size_t)gk * 512 + gn];
        else if (gn < 576) v = Ws[(size_t)gk * 64 + (gn - 512)];
        else               v = 0.f;
        tile[kk][nn] = v;
    }
    __syncthreads();
#pragma unroll
    for (int i = 0; i < 16; i++) {
        int nn = a + i * 4, kk = b;
        float v = tile[kk][nn];
        ushort hi = f2bf(v);
        ushort lo = f2bf(v - bf2f(hi));
        Bth[(size_t)(n0 + nn) * 512 + k0 + kk] = hi;
        Btl[(size_t)(n0 + nn) * 512 + k0 + kk] = lo;
    }
}

// ---------------------------------------------------------------- fused MFMA GEMM: [h1 | skip] = bn(x) @ [W1 | Ws]
// split-bf16 3-product; tile 128x128, BK=32, 4 waves.
// Combined hi/lo LDS buffer: row r = 128B = 8 slots of 16B; phys slot sp holds
// logical slot sl = sp ^ (r&7)  (sl 0-3: hi k-group sl, sl 4-7: lo k-group sl-4).
// -> staging source stays 64B-segment coalesced AND ds_read_b128 is conflict-free.
// GAT1 scores (ss1/sd1) fused into the epilogue (block bx<4 covers exactly head bx).
__global__ __launch_bounds__(256) void mfma_gemm_k(
    const ushort* __restrict__ Ah, const ushort* __restrict__ Al,
    const ushort* __restrict__ Bth, const ushort* __restrict__ Btl,
    const float* __restrict__ bs, const float* __restrict__ as1, const float* __restrict__ ad1,
    float* __restrict__ h1, float* __restrict__ skip,
    float* __restrict__ ss1, float* __restrict__ sd1,
    int M, int K) {
    __shared__ ushort A_s[128 * 64];   // 16 KB combined hi|lo
    __shared__ ushort B_s[128 * 64];
    __shared__ float s1buf[128], s2buf[128];
    int t = threadIdx.x;
    int w = t >> 6, l = t & 63;

    // bijective XCD-chunked swizzle (m204)
    int nwg = gridDim.x;
    int q = nwg >> 3, r = nwg & 7;
    int xcd = blockIdx.x & 7, lid = blockIdx.x >> 3;
    int wg = (xcd < r) ? xcd * (q + 1) + lid : r * (q + 1) + (xcd - r) * q + lid;
    int by = wg / 5, bx = wg % 5;      // logical grid 5 (n) x 157 (m)
    int bm = by * 128;
    int n0 = bx * 128;
    int r0 = (w & 1) * 64, c0 = (w >> 1) * 64;

    f32x4 acc[4][4] = {};

    // staging: call c (0..3): thread t -> phys elem c*2048 + t*8
    //   row = c*32 + (t>>3), phys slot = t&7, logical slot sl = (t&7) ^ ((t>>3)&7)
    int sl = (t & 7) ^ ((t >> 3) & 7);
    const ushort* aArr = (sl < 4) ? Ah : Al;
    const ushort* bArr = (sl < 4) ? Bth : Btl;
    int ko = (sl & 3) * 8;
    size_t asrc[4], bsrc[4];
#pragma unroll
    for (int c = 0; c < 4; c++) {
        int rr = c * 32 + (t >> 3);
        asrc[c] = (size_t)(bm + rr) * 512 + ko;
        bsrc[c] = (size_t)(n0 + rr) * 512 + ko;
    }
    int d0 = t * 8;

    for (int kt = 0; kt < K; kt += 32) {
#pragma unroll
        for (int c = 0; c < 4; c++) gload_lds16(aArr + asrc[c] + kt, &A_s[c * 2048 + d0]);
#pragma unroll
        for (int c = 0; c < 4; c++) gload_lds16(bArr + bsrc[c] + kt, &B_s[c * 2048 + d0]);
        __syncthreads();

        short8 ah[4], al4[4], bh[4], bl[4];
        int lr = l & 15, kg = l >> 4;
        int spa = kg ^ (lr & 7);       // r&7 == lr&7 (r0, f*16 are multiples of 8... of 16)
#pragma unroll
        for (int f = 0; f < 4; f++) {
            int ra = (r0 + f * 16 + lr) * 64;
            ah[f]  = *(const short8*)&A_s[ra + spa * 8];
            al4[f] = *(const short8*)&A_s[ra + (spa ^ 4) * 8];
            int rb = (c0 + f * 16 + lr) * 64;
            bh[f] = *(const short8*)&B_s[rb + spa * 8];
            bl[f] = *(const short8*)&B_s[rb + (spa ^ 4) * 8];
        }
#pragma unroll
        for (int fm = 0; fm < 4; fm++)
#pragma unroll
            for (int fn = 0; fn < 4; fn++) {
                acc[fm][fn] = __builtin_amdgcn_mfma_f32_16x16x32_bf16(ah[fm], bh[fn], acc[fm][fn], 0, 0, 0);
                acc[fm][fn] = __builtin_amdgcn_mfma_f32_16x16x32_bf16(ah[fm], bl[fn], acc[fm][fn], 0, 0, 0);
                acc[fm][fn] = __builtin_amdgcn_mfma_f32_16x16x32_bf16(al4[fm], bh[fn], acc[fm][fn], 0, 0, 0);
            }
        __syncthreads();
    }

    int lr = l & 15, kg = l >> 4;
    // ---- C write. C/D layout: col=lane&15, row=(lane>>4)*4+reg
#pragma unroll
    for (int fm = 0; fm < 4; fm++) {
        int row_base = bm + r0 + fm * 16 + kg * 4;
#pragma unroll
        for (int fn = 0; fn < 4; fn++) {
            int col = n0 + c0 + fn * 16 + lr;
#pragma unroll
            for (int r2 = 0; r2 < 4; r2++) {
                int row = row_base + r2;
                if (row < M) {
                    float v = acc[fm][fn][r2];
                    if (col < 512) h1[(size_t)row * 512 + col] = v;
                    else if (col < 576) skip[(size_t)row * 64 + (col - 512)] = fmaxf(v + bs[col - 512], 0.f);
                }
            }
        }
    }

    // ---- fused GAT1 scores: block bx<4 holds all 128 cols of head bx
    if (t < 128) { s1buf[t] = 0.f; s2buf[t] = 0.f; }
    __syncthreads();
    if (bx < 4) {
        float aw_[4], dw_[4];
#pragma unroll
        for (int fn = 0; fn < 4; fn++) {
            int col = n0 + c0 + fn * 16 + lr;
            aw_[fn] = as1[col];
            dw_[fn] = ad1[col];
        }
#pragma unroll
        for (int fm = 0; fm < 4; fm++)
#pragma unroll
            for (int r2 = 0; r2 < 4; r2++) {
                float p1 = acc[fm][0][r2] * aw_[0] + acc[fm][1][r2] * aw_[1] +
                           acc[fm][2][r2] * aw_[2] + acc[fm][3][r2] * aw_[3];
                float p2 = acc[fm][0][r2] * dw_[0] + acc[fm][1][r2] * dw_[1] +
                           acc[fm][2][r2] * dw_[2] + acc[fm][3][r2] * dw_[3];
#pragma unroll
                for (int off = 1; off < 16; off <<= 1) {
                    p1 += __shfl_xor(p1, off);
                    p2 += __shfl_xor(p2, off);
                }
                if (lr == 0) {
                    int rloc = r0 + fm * 16 + kg * 4 + r2;
                    atomicAdd(&s1buf[rloc], p1);
                    atomicAdd(&s2buf[rloc], p2);
                }
            }
    }
    __syncthreads();
    if (bx < 4 && t < 128 && bm + t < M) {
        ss1[(size_t)(bm + t) * 4 + bx] = s1buf[t];
        sd1[(size_t)(bm + t) * 4 + bx] = s2buf[t];
    }
}

// ---------------------------------------------------------------- small GEMM, W cached in LDS, 8 rows/iter
template <int K, int NOUT>
__global__ __launch_bounds__(NOUT) void rowgemm_k(const float* __restrict__ X, const float* __restrict__ W,
                                                  float* __restrict__ out, int N) {
    __shared__ float Ws[K * NOUT];
    __shared__ float Xs[8][K];
    int c = threadIdx.x;
    for (int i = c; i < K * NOUT; i += NOUT) Ws[i] = W[i];
    for (int r0 = blockIdx.x * 8; r0 < N; r0 += gridDim.x * 8) {
        int nr = min(8, N - r0);
        __syncthreads();
        for (int i = c; i < nr * K; i += NOUT) Xs[i / K][i % K] = X[(size_t)r0 * K + i];
        __syncthreads();
        float acc[8] = {};
        for (int k = 0; k < K; k++) {
            float w = Ws[k * NOUT + c];
#pragma unroll
            for (int r = 0; r < 8; r++) acc[r] += Xs[r][k] * w;
        }
        for (int r = 0; r < nr; r++) out[(size_t)(r0 + r) * NOUT + c] = acc[r];
    }
}

// ---------------------------------------------------------------- attention scores (GAT2 only)
template <int H, int C>
__global__ __launch_bounds__(256) void scores_k(const float* __restrict__ h, const float* __restrict__ a_src,
                                                const float* __restrict__ a_dst, float* __restrict__ ss,
                                                float* __restrict__ sd, int N) {
    int wid = (blockIdx.x * blockDim.x + threadIdx.x) >> 6;
    int lane = threadIdx.x & 63;
    if (wid >= N * H) return;
    int hh = wid % H;
    const float* hp = h + (size_t)(wid / H) * (H * C) + hh * C;
    float s1 = 0.f, s2 = 0.f;
    for (int c = lane; c < C; c += 64) {
        float v = hp[c];
        s1 += v * a_src[hh * C + c];
        s2 += v * a_dst[hh * C + c];
    }
#pragma unroll
    for (int off = 32; off; off >>= 1) {
        s1 += __shfl_down(s1, off);
        s2 += __shfl_down(s2, off);
    }
    if (lane == 0) { ss[wid] = s1; sd[wid] = s2; }
}

// ---------------------------------------------------------------- GAT agg: wave-parallel online softmax (+e-cache),
// gather, mean, bias, LN (shuffle), relu.  Requires C/H == 32.
template <int H, int C>
__global__ __launch_bounds__(C) void gat_agg_k(const float* __restrict__ h, const float* __restrict__ ss,
                                               const float* __restrict__ sd, const float* __restrict__ bias,
                                               const float* __restrict__ g, const float* __restrict__ be,
                                               const int* __restrict__ rp, const int* __restrict__ csr_src,
                                               float* __restrict__ out, int N) {
    int n = blockIdx.x;
    int tid = threadIdx.x;
    __shared__ float m_s[H], s_s[H], red[4];
    __shared__ int srcs[64];
    __shared__ float aw[64 * H];
    int e0 = rp[n], deg = rp[n + 1] - e0;
    bool small = (deg <= 64);
    int hh = tid >> 5, l = tid & 31;

    if (small && tid < deg) srcs[tid] = csr_src[e0 + tid];
    __syncthreads();

    float sdv = sd[n * H + hh];
    float m = -1e30f, s = 0.f;
    for (int k = l; k < deg; k += 32) {
        int src = small ? srcs[k] : csr_src[e0 + k];
        float e = ss[src * H + hh] + sdv;
        e = (e > 0.f) ? e : 0.2f * e;
        if (small) aw[k * H + hh] = e;
        float mn = fmaxf(m, e);
        s = s * __expf(m - mn) + __expf(e - mn);
        m = mn;
    }
#pragma unroll
    for (int off = 16; off; off >>= 1) {
        float mo = __shfl_xor(m, off), so = __shfl_xor(s, off);
        float mn = fmaxf(m, mo);
        s = s * __expf(m - mn) + so * __expf(mo - mn);
        m = mn;
    }
    if (l == 0) { m_s[hh] = m; s_s[hh] = s + 1e-16f; }
    __syncthreads();

    float v = 0.f;
    if (small) {
        for (int idx = tid; idx < deg * H; idx += C) {
            int h2 = idx & (H - 1);
            aw[idx] = __expf(aw[idx] - m_s[h2]) / s_s[h2];
        }
        __syncthreads();
        for (int k = 0; k < deg; k++) {
            const float* hp = h + (size_t)srcs[k] * (H * C) + tid;
#pragma unroll
            for (int h2 = 0; h2 < H; h2++) v += aw[k * H + h2] * hp[h2 * C];
        }
    } else {
        for (int t0 = 0; t0 < deg; t0 += 64) {
            int tl = min(64, deg - t0);
            __syncthreads();
            if (tid < tl) srcs[tid] = csr_src[e0 + t0 + tid];
            __syncthreads();
            for (int idx = tid; idx < tl * H; idx += C) {
                int k = idx / H, h2 = idx & (H - 1);
                float e = ss[srcs[k] * H + h2] + sd[n * H + h2];
                e = (e > 0.f) ? e : 0.2f * e;
                aw[idx] = __expf(e - m_s[h2]) / s_s[h2];
            }
            __syncthreads();
            for (int k = 0; k < tl; k++) {
                const float* hp = h + (size_t)srcs[k] * (H * C) + tid;
#pragma unroll
                for (int h2 = 0; h2 < H; h2++) v += aw[k * H + h2] * hp[h2 * C];
            }
        }
    }

    v = v * (1.f / H) + bias[tid];
    float t1 = v;
#pragma unroll
    for (int off = 32; off; off >>= 1) t1 += __shfl_xor(t1, off);
    float mu;
    if (C == 128) {
        if ((tid & 63) == 0) red[tid >> 6] = t1;
        __syncthreads();
        mu = (red[0] + red[1]) * (1.f / C);
    } else {
        mu = t1 * (1.f / C);
    }
    float d = v - mu;
    float t2 = d * d;
#pragma unroll
    for (int off = 32; off; off >>= 1) t2 += __shfl_xor(t2, off);
    float var;
    if (C == 128) {
        if ((tid & 63) == 0) red[2 + (tid >> 6)] = t2;
        __syncthreads();
        var = (red[2] + red[3]) * (1.f / C);
    } else {
        var = t2 * (1.f / C);
    }
    float y = d * rsqrtf(var + 1e-5f) * g[tid] + be[tid];
    out[(size_t)n * C + tid] = fmaxf(y, 0.f);
}

// ---------------------------------------------------------------- GCN aggregation + bias + relu (GCN1)
template <int C>
__global__ __launch_bounds__(C) void gcn_agg_k(const float* __restrict__ h, const float* __restrict__ dis,
                                               const float* __restrict__ bias, const int* __restrict__ rp,
                                               const int* __restrict__ csr_src, float* __restrict__ out, int N) {
    int n = blockIdx.x;
    int tid = threadIdx.x;
    __shared__ int srcs[64];
    __shared__ float w[64];
    int e0 = rp[n], deg = rp[n + 1] - e0;
    float dn = dis[n];
    float acc = 0.f;
    for (int t0 = 0; t0 < deg; t0 += 64) {
        int tl = min(64, deg - t0);
        if (tid < tl) {
            int s = csr_src[e0 + t0 + tid];
            srcs[tid] = s;
            w[tid] = dis[s] * dn;
        }
        __syncthreads();
        for (int k = 0; k < tl; k++) acc += w[k] * h[(size_t)srcs[k] * C + tid];
        __syncthreads();
    }
    out[(size_t)n * C + tid] = fmaxf(acc + bias[tid], 0.f);
}

// ---------------------------------------------------------------- final fused: gcn_agg2 -> fusion+LN -> classifier
__global__ __launch_bounds__(64) void final_fused_k(
    const float* __restrict__ hg2, const float* __restrict__ dis, const float* __restrict__ bg2,
    const int* __restrict__ rp, const int* __restrict__ csr_src,
    const float* __restrict__ x1g, const float* __restrict__ Wf, const float* __restrict__ bf,
    const float* __restrict__ skip, const float* __restrict__ g3, const float* __restrict__ be3,
    const float* __restrict__ Wc1, const float* __restrict__ bc1, const float* __restrict__ gbn,
    const float* __restrict__ bbn, const float* __restrict__ rmb, const float* __restrict__ rvb,
    const float* __restrict__ Wc2, const float* __restrict__ bc2, float* __restrict__ out, int N) {
    int n = blockIdx.x;
    int tid = threadIdx.x;
    __shared__ int srcs[64];
    __shared__ float w[64];
    __shared__ float cat[192];
    __shared__ float fbuf[64];
    __shared__ float hbuf[32];
    int e0 = rp[n], deg = rp[n + 1] - e0;
    float dn = dis[n];
    float acc = 0.f;
    for (int t0 = 0; t0 < deg; t0 += 64) {
        int tl = min(64, deg - t0);
        if (tid < tl) {
            int s = csr_src[e0 + t0 + tid];
            srcs[tid] = s;
            w[tid] = dis[s] * dn;
        }
        __syncthreads();
        for (int k = 0; k < tl; k++) acc += w[k] * hg2[(size_t)srcs[k] * 64 + tid];
        __syncthreads();
    }
    float x2gv = fmaxf(acc + bg2[tid], 0.f);
    cat[tid] = x1g[(size_t)n * 128 + tid];
    cat[64 + tid] = x1g[(size_t)n * 128 + 64 + tid];
    cat[128 + tid] = x2gv;
    __syncthreads();
    float fa = bf[tid];
    for (int j = 0; j < 192; j++) fa += cat[j] * Wf[j * 64 + tid];
    fa = fmaxf(fa, 0.f) + skip[(size_t)n * 64 + tid];
    float t1 = fa;
#pragma unroll
    for (int off = 32; off; off >>= 1) t1 += __shfl_xor(t1, off);
    float mu = t1 * (1.f / 64.f);
    float d = fa - mu;
    float t2 = d * d;
#pragma unroll
    for (int off = 32; off; off >>= 1) t2 += __shfl_xor(t2, off);
    float var = t2 * (1.f / 64.f);
    fbuf[tid] = d * rsqrtf(var + 1e-5f) * g3[tid] + be3[tid];
    __syncthreads();
    if (tid < 32) {
        float a = bc1[tid];
        for (int j = 0; j < 64; j++) a += fbuf[j] * Wc1[j * 32 + tid];
        a = (a - rmb[tid]) * rsqrtf(rvb[tid] + 1e-5f) * gbn[tid] + bbn[tid];
        hbuf[tid] = fmaxf(a, 0.f);
    }
    __syncthreads();
    if (tid < 5) {
        float a = bc2[tid];
        for (int j = 0; j < 32; j++) a += hbuf[j] * Wc2[j * 5 + tid];
        out[(size_t)n * 5 + tid] = a;
    }
}

// ================================================================ launch
extern "C" void kernel_launch(void* const* d_in, const int* in_sizes, int n_in,
                              void* d_out, int out_size, void* d_ws, size_t ws_size,
                              hipStream_t stream) {
    const float* x   = (const float*)d_in[0];
    const int*   ei  = (const int*)d_in[1];
    const float* gin = (const float*)d_in[2];
    const float* bti = (const float*)d_in[3];
    const float* rmi = (const float*)d_in[4];
    const float* rvi = (const float*)d_in[5];
    const float* W1  = (const float*)d_in[6];
    const float* as1 = (const float*)d_in[7];
    const float* ad1 = (const float*)d_in[8];
    const float* b1  = (const float*)d_in[9];
    const float* Wg1 = (const float*)d_in[10];
    const float* bg1 = (const float*)d_in[11];
    const float* W2  = (const float*)d_in[12];
    const float* as2 = (const float*)d_in[13];
    const float* ad2 = (const float*)d_in[14];
    const float* b2  = (const float*)d_in[15];
    const float* Wg2 = (const float*)d_in[16];
    const float* bg2 = (const float*)d_in[17];
    const float* Ws  = (const float*)d_in[18];
    const float* bs  = (const float*)d_in[19];
    const float* Wf  = (const float*)d_in[20];
    const float* bf  = (const float*)d_in[21];
    const float* g1  = (const float*)d_in[22];
    const float* be1 = (const float*)d_in[23];
    const float* g2  = (const float*)d_in[24];
    const float* be2 = (const float*)d_in[25];
    const float* g3  = (const float*)d_in[26];
    const float* be3 = (const float*)d_in[27];
    const float* Wc1 = (const float*)d_in[28];
    const float* bc1 = (const float*)d_in[29];
    const float* gbn = (const float*)d_in[30];
    const float* bbn = (const float*)d_in[31];
    const float* rmb = (const float*)d_in[32];
    const float* rvb = (const float*)d_in[33];
    const float* Wc2 = (const float*)d_in[34];
    const float* bc2 = (const float*)d_in[35];
    float* out = (float*)d_out;

    const int N = in_sizes[0] / F_IN;          // 20000
    const int E0 = in_sizes[1] / 2;            // 160000
    const int Etot = E0 + N;                   // 180000
    const int Mpad = 20096;                    // 157*128

    // ---- workspace carve-up (bump allocator, 256B aligned)
    char* wp = (char*)d_ws;
    auto alloc = [&](size_t bytes) -> void* {
        void* p = (void*)wp;
        wp += (bytes + 255) & ~(size_t)255;
        return p;
    };
    float* h1   = (float*)alloc((size_t)N * 512 * 4);     // region aliased after GAT1
    ushort* Ah  = (ushort*)alloc((size_t)Mpad * 512 * 2); // dead after GEMM -> aliased below
    ushort* Al  = (ushort*)alloc((size_t)Mpad * 512 * 2);
    ushort* Bth = (ushort*)alloc((size_t)640 * 512 * 2);
    ushort* Btl = (ushort*)alloc((size_t)640 * 512 * 2);
    float* skip = (float*)alloc((size_t)N * 64 * 4);
    float* ss1  = (float*)alloc((size_t)N * 4 * 4);
    float* sd1  = (float*)alloc((size_t)N * 4 * 4);
    float* ss2  = (float*)alloc((size_t)N * 2 * 4);
    float* sd2  = (float*)alloc((size_t)N * 2 * 4);
    float* dis  = (float*)alloc((size_t)N * 4);
    float* sc   = (float*)alloc((size_t)F_IN * 4);
    float* sh   = (float*)alloc((size_t)F_IN * 4);
    int* deg    = (int*)alloc((size_t)N * 4);
    int* rp     = (int*)alloc((size_t)(N + 1) * 4);
    int* fp     = (int*)alloc((size_t)(N + 1) * 4);
    int* csr    = (int*)alloc((size_t)Etot * 4);
    // aliases inside h1's region (h1 dead after GAT1 aggregation)
    float* hg1 = h1;                    // N*128
    float* x1g = h1 + (size_t)N * 128;  // N*128
    float* h2  = h1 + (size_t)N * 256;  // N*128
    float* x2  = h1 + (size_t)N * 384;  // N*64
    float* hg2 = h1 + (size_t)N * 448;  // N*64
    // aliases inside Ah region (Ah/Al dead after mfma_gemm)
    float* x1  = (float*)Ah;            // N*128

    // ---- CSR build + BN prep + splits
    zero_int_k<<<(N + 255) / 256, 256, 0, stream>>>(deg, N);
    hist_k<<<(Etot + 255) / 256, 256, 0, stream>>>(ei, E0, N, deg);
    scan_k<<<1, 1024, 0, stream>>>(deg, rp, fp, dis, N, Etot);
    scatter_k<<<(Etot + 255) / 256, 256, 0, stream>>>(ei, E0, N, fp, csr);
    bnprep_k<<<2, 256, 0, stream>>>(gin, bti, rmi, rvi, sc, sh, F_IN);
    splitA_k<<<(int)(((size_t)Mpad * 512 / 4 + 255) / 256), 256, 0, stream>>>(x, sc, sh, Ah, Al, N, Mpad);
    splitBt_k<<<dim3(10, 8), 256, 0, stream>>>(W1, Ws, Bth, Btl);

    // ---- fused GEMM: [h1 | skip] + GAT1 scores
    mfma_gemm_k<<<785, 256, 0, stream>>>(Ah, Al, Bth, Btl, bs, as1, ad1, h1, skip, ss1, sd1, N, 512);

    // ---- GAT1 aggregation
    gat_agg_k<4, 128><<<N, 128, 0, stream>>>(h1, ss1, sd1, b1, g1, be1, rp, csr, x1, N);

    // ---- GCN1
    rowgemm_k<128, 128><<<1280, 128, 0, stream>>>(x1, Wg1, hg1, N);
    gcn_agg_k<128><<<N, 128, 0, stream>>>(hg1, dis, bg1, rp, csr, x1g, N);

    // ---- GAT2
    rowgemm_k<128, 128><<<1280, 128, 0, stream>>>(x1g, W2, h2, N);
    scores_k<2, 64><<<(N * 2 + 3) / 4, 256, 0, stream>>>(h2, as2, ad2, ss2, sd2, N);
    gat_agg_k<2, 64><<<N, 64, 0, stream>>>(h2, ss2, sd2, b2, g2, be2, rp, csr, x2, N);

    // ---- GCN2 dense part
    rowgemm_k<64, 64><<<1280, 64, 0, stream>>>(x2, Wg2, hg2, N);

    // ---- GCN2 agg + fusion + LN + classifier (fused, row-local)
    final_fused_k<<<N, 64, 0, stream>>>(hg2, dis, bg2, rp, csr, x1g, Wf, bf, skip, g3, be3,
                                        Wc1, bc1, gbn, bbn, rmb, rvb, Wc2, bc2, out, N);
}